// Round 7
// baseline (480.638 us; speedup 1.0000x reference)
//
#include <hip/hip_runtime.h>
#include <math.h>

// Problem constants
#define HW   16384        // 128*128
#define CC   256
#define cC   64
#define BB   16
#define CHW  (CC*HW)      // 4194304
#define cHW  (cC*HW)      // 1048576

// ws float offsets (ws_size = 1 GiB)
#define WS_TB    0                      // t bf16
#define WS_H1B   8388608                // h1 bf16
#define WS_RAWB  16777216               // conv2 raw bf16
#define WS_W2E   50331648
#define WS_K1E   (WS_W2E + 5184)
#define WS_GN1A  (WS_K1E + 16)
#define WS_GNSA  (WS_GN1A + 512)
#define WS_GN2A  (WS_GNSA + 512)
#define WS_SC1   (WS_GN2A + 512)
#define WS_SH1   (WS_SC1 + 1024)
#define WS_SCS   (WS_SH1 + 1024)
#define WS_SHS   (WS_SCS + 1024)
#define WS_SC2   (WS_SHS + 1024)
#define WS_SH2   (WS_SC2 + 4096)
#define WS_W1P   (WS_SH2 + 4096)
#define WS_W2P   (WS_W1P + 8192)

typedef __attribute__((ext_vector_type(8))) short bf16x8;
typedef __attribute__((ext_vector_type(4))) float f32x4;
typedef __attribute__((ext_vector_type(8))) unsigned short u16x8;

__device__ inline unsigned short f2bf(float f) {
    union { float f; unsigned u; } c; c.f = f;
    unsigned r = c.u + 0x7FFFu + ((c.u >> 16) & 1u);
    return (unsigned short)(r >> 16);
}
__device__ inline float bf2f(unsigned short h) {
    union { unsigned u; float f; } c; c.u = ((unsigned)h) << 16; return c.f;
}

// ---------------------------------------------------------------------------
// K0: effective kernels; zero GN accum; pack conv weights into MFMA frag order
// ---------------------------------------------------------------------------
__global__ void k_setup(const float* __restrict__ W1, const float* __restrict__ W2,
                        const float* __restrict__ c1w, const float* __restrict__ c2w,
                        float* __restrict__ k1e, float* __restrict__ w2e,
                        float* __restrict__ accz, unsigned short* __restrict__ w1p,
                        unsigned short* __restrict__ w2p) {
    __shared__ float tapsum[81];
    __shared__ float a2s[4];
    int tdx = threadIdx.x;
    for (int i = tdx; i < 1536; i += 128) accz[i] = 0.f;
    for (int e = tdx; e < 16384; e += 128) {
        int fi = e >> 9, rem = e & 511;
        int l = rem >> 3, j = rem & 7;
        int ks = fi >> 2, nf = fi & 3;
        int c = ks * 32 + (l >> 4) * 8 + j;
        int oc = nf * 16 + (l & 15);
        w1p[e] = f2bf(c1w[oc * 256 + c]);
    }
    for (int e = tdx; e < 16384; e += 128) {
        int fi = e >> 9, rem = e & 511;
        int l = rem >> 3, j = rem & 7;
        int ks = fi >> 4, nfg = fi & 15;
        int c = ks * 32 + (l >> 4) * 8 + j;
        int oc = nfg * 16 + (l & 15);
        w2p[e] = f2bf(c2w[oc * 64 + c]);
    }
    if (tdx < 81) {
        float s = 0.f;
        for (int ch = 0; ch < 64; ++ch) s += W2[ch * 81 + tdx];
        tapsum[tdx] = s;
    }
    __syncthreads();
    if (tdx == 0) {
        float ring[4] = {0.f, 0.f, 0.f, 0.f};
        for (int i = 0; i < 9; ++i)
            for (int j = 0; j < 9; ++j) {
                int d = max(abs(i - 4), abs(j - 4));
                int r = (d <= 1) ? 0 : (d - 1);
                ring[r] += tapsum[i * 9 + j];
            }
        float den2[4] = {576.f, 1024.f, 1536.f, 2048.f};
        float v[4], mx = -1e30f;
        for (int p = 0; p < 4; ++p) { v[p] = ring[p] / den2[p]; mx = fmaxf(mx, v[p]); }
        float se = 0.f;
        for (int p = 0; p < 4; ++p) { v[p] = expf(v[p] - mx); se += v[p]; }
        for (int p = 0; p < 4; ++p) a2s[p] = v[p] / se;
        float k1[9];
        for (int k = 0; k < 9; ++k) k1[k] = W1[k];
        float num[4];
        num[0] = k1[3] + k1[4] + k1[5];
        num[1] = k1[2] + k1[6];
        num[2] = k1[1] + k1[7];
        num[3] = k1[0] + k1[8];
        float den1[4] = {3.f, 2.f, 2.f, 2.f};
        mx = -1e30f;
        for (int p = 0; p < 4; ++p) { v[p] = num[p] / den1[p]; mx = fmaxf(mx, v[p]); }
        se = 0.f;
        for (int p = 0; p < 4; ++p) { v[p] = expf(v[p] - mx); se += v[p]; }
        float a1[4];
        for (int p = 0; p < 4; ++p) a1[p] = v[p] / se;
        float s1arr[5];
        s1arr[0] = 1.f; s1arr[1] = 1.f;
        s1arr[4] = a1[3]; s1arr[3] = a1[2] + a1[3]; s1arr[2] = a1[1] + s1arr[3];
        for (int k = 0; k < 9; ++k) { int d = abs(k - 4); k1e[k] = k1[k] * s1arr[d]; }
    }
    __syncthreads();
    float s2arr[5];
    s2arr[0] = 1.f; s2arr[1] = 1.f;
    s2arr[4] = a2s[3]; s2arr[3] = a2s[2] + a2s[3]; s2arr[2] = a2s[1] + s2arr[3];
    for (int idx = tdx; idx < 64 * 81; idx += 128) {
        int tap = idx % 81;
        int i = tap / 9, j = tap - i * 9;
        int d = max(abs(i - 4), abs(j - 4));
        w2e[idx] = W2[idx] * s2arr[d];
    }
}

// ---------------------------------------------------------------------------
// K1: conv1 (1x1, 256->64) via bf16 MFMA -> h1 bf16 [ch][p] ; GN1 sums
// ---------------------------------------------------------------------------
__global__ __launch_bounds__(256) void k_conv1(const float* __restrict__ x,
        const unsigned short* __restrict__ w1p, const float* __restrict__ b1,
        unsigned short* __restrict__ h1, float* __restrict__ gn1a) {
    int bid = blockIdx.x;
    int b = bid >> 6, pt = bid & 63;
    int tid = threadIdx.x;
    int w = tid >> 6, lane = tid & 63;
    int l15 = lane & 15, lg = lane >> 4;
    int p_wave = pt * 256 + w * 64;
    const bf16x8* w1v = (const bf16x8*)w1p;
    f32x4 acc[4][4];
#pragma unroll
    for (int mf = 0; mf < 4; ++mf)
#pragma unroll
        for (int nf = 0; nf < 4; ++nf) acc[mf][nf] = (f32x4){0.f, 0.f, 0.f, 0.f};
    const float* xb = x + b * CHW;
#pragma unroll 1
    for (int ks = 0; ks < 8; ++ks) {
        int c0 = ks * 32 + lg * 8;
        bf16x8 afr[4];
#pragma unroll
        for (int mf = 0; mf < 4; ++mf) {
            const float* xp = xb + c0 * HW + p_wave + mf * 16 + l15;
            bf16x8 a;
#pragma unroll
            for (int j = 0; j < 8; ++j) a[j] = (short)f2bf(__builtin_nontemporal_load(xp + j * HW));
            afr[mf] = a;
        }
#pragma unroll
        for (int nf = 0; nf < 4; ++nf) {
            bf16x8 bfr = w1v[(ks * 4 + nf) * 64 + lane];
#pragma unroll
            for (int mf = 0; mf < 4; ++mf)
                acc[mf][nf] = __builtin_amdgcn_mfma_f32_16x16x32_bf16(afr[mf], bfr, acc[mf][nf], 0, 0, 0);
        }
    }
    __shared__ float red[4][16][2];
    unsigned short* hb = h1 + b * cHW;
#pragma unroll
    for (int nf = 0; nf < 4; ++nf) {
        int oc = nf * 16 + l15;
        float bias = b1[oc];
        float s = 0.f, ss = 0.f;
#pragma unroll
        for (int mf = 0; mf < 4; ++mf) {
            f32x4 v = acc[mf][nf];
            v[0] += bias; v[1] += bias; v[2] += bias; v[3] += bias;
            ushort4 hv = make_ushort4(f2bf(v[0]), f2bf(v[1]), f2bf(v[2]), f2bf(v[3]));
            *(ushort4*)(hb + oc * HW + p_wave + mf * 16 + lg * 4) = hv;
            s += v[0] + v[1] + v[2] + v[3];
            ss += v[0] * v[0] + v[1] * v[1] + v[2] * v[2] + v[3] * v[3];
        }
        s += __shfl_xor(s, 16, 64); ss += __shfl_xor(ss, 16, 64);
        s += __shfl_xor(s, 32, 64); ss += __shfl_xor(ss, 32, 64);
        s += __shfl_xor(s, 1, 64);  ss += __shfl_xor(ss, 1, 64);
        s += __shfl_xor(s, 2, 64);  ss += __shfl_xor(ss, 2, 64);
        if (lg == 0 && (l15 & 3) == 0) {
            int g = nf * 4 + (l15 >> 2);
            red[w][g][0] = s; red[w][g][1] = ss;
        }
    }
    __syncthreads();
    if (tid < 32) {
        int g = tid >> 1, c = tid & 1;
        float v = red[0][g][c] + red[1][g][c] + red[2][g][c] + red[3][g][c];
        atomicAdd(&gn1a[(b * 16 + g) * 2 + c], v);
    }
}

// ---------------------------------------------------------------------------
// GN finalize
// ---------------------------------------------------------------------------
__global__ void k_gnfin(const float* __restrict__ accum, const float* __restrict__ gw,
                        const float* __restrict__ gb, float* __restrict__ scale,
                        float* __restrict__ shift, int nent, int chbits, int gshift,
                        float inv_n) {
    int idx = blockIdx.x * blockDim.x + threadIdx.x;
    if (idx >= nent) return;
    int chm = (1 << chbits) - 1;
    int ch = idx & chm, b = idx >> chbits, g = ch >> gshift;
    float s = accum[(b * 16 + g) * 2], ss = accum[(b * 16 + g) * 2 + 1];
    float mu = s * inv_n;
    float var = ss * inv_n - mu * mu;
    float rstd = rsqrtf(var + 1e-5f);
    float sc = gw[ch] * rstd;
    scale[idx] = sc;
    shift[idx] = gb[ch] - mu * sc;
}

// ---------------------------------------------------------------------------
// K3: channel-dim 9-tap conv (pad 4) -> t (bf16) ; 4 positions/thread
// ---------------------------------------------------------------------------
__global__ __launch_bounds__(256) void k_x3(const unsigned short* __restrict__ h1,
        const float* __restrict__ scale1, const float* __restrict__ shift1,
        const float* __restrict__ k1e, unsigned short* __restrict__ t) {
    int i = blockIdx.x * 256 + threadIdx.x;     // 0..65535
    int b = i >> 12, p = (i & 4095) * 4;
    __shared__ float lsc[64], lsh[64], lke[9];
    if (threadIdx.x < 64) {
        lsc[threadIdx.x] = scale1[b * 64 + threadIdx.x];
        lsh[threadIdx.x] = shift1[b * 64 + threadIdx.x];
    }
    if (threadIdx.x < 9) lke[threadIdx.x] = k1e[threadIdx.x];
    __syncthreads();
    const unsigned short* hb = h1 + b * cHW + p;
    float4 win[9];
#pragma unroll
    for (int k = 0; k < 9; ++k) {
        int ch = k - 4;
        if (ch >= 0) {
            ushort4 hv = *(const ushort4*)(hb + ch * HW);
            float s = lsc[ch], h = lsh[ch];
            win[k] = make_float4(fmaf(bf2f(hv.x), s, h), fmaf(bf2f(hv.y), s, h),
                                 fmaf(bf2f(hv.z), s, h), fmaf(bf2f(hv.w), s, h));
        } else win[k] = make_float4(0.f, 0.f, 0.f, 0.f);
    }
    unsigned short* tb = t + b * cHW + p;
#pragma unroll
    for (int ch = 0; ch < 64; ++ch) {
        float4 s = make_float4(0.f, 0.f, 0.f, 0.f);
#pragma unroll
        for (int k = 0; k < 9; ++k) {
            float kv = lke[k];
            s.x = fmaf(win[k].x, kv, s.x);
            s.y = fmaf(win[k].y, kv, s.y);
            s.z = fmaf(win[k].z, kv, s.z);
            s.w = fmaf(win[k].w, kv, s.w);
        }
        *(ushort4*)(tb + ch * HW) = make_ushort4(f2bf(s.x), f2bf(s.y), f2bf(s.z), f2bf(s.w));
#pragma unroll
        for (int k = 0; k < 8; ++k) win[k] = win[k + 1];
        int nc = ch + 5;
        if (nc < 64) {
            ushort4 hv = *(const ushort4*)(hb + nc * HW);
            float sN = lsc[nc], hN = lsh[nc];
            win[8] = make_float4(fmaf(bf2f(hv.x), sN, hN), fmaf(bf2f(hv.y), sN, hN),
                                 fmaf(bf2f(hv.z), sN, hN), fmaf(bf2f(hv.w), sN, hN));
        } else win[8] = make_float4(0.f, 0.f, 0.f, 0.f);
    }
}

// ---------------------------------------------------------------------------
// K4: depthwise 9x9 spatial conv ; t += x_sa (bf16 RMW) ; GN_s sums
// block = (b, ch, 32-row tile) ; thread = 4 rows x 4 cols ; tile 40x136 f32
// ---------------------------------------------------------------------------
__global__ __launch_bounds__(256) void k_xsa(const unsigned short* __restrict__ h1,
        const float* __restrict__ scale1, const float* __restrict__ shift1,
        const float* __restrict__ w2e, unsigned short* __restrict__ t,
        float* __restrict__ gnsa) {
    int bid = blockIdx.x;
    int b = bid >> 8, ch = (bid >> 2) & 63, rt = bid & 3;
    int r0 = rt * 32;
    int tid = threadIdx.x;
    const float sc = scale1[b * 64 + ch];
    const float sh = shift1[b * 64 + ch];
    const unsigned short* hp = h1 + b * cHW + ch * HW;
    __shared__ float tile[40 * 136];            // 21.25 KB
    for (int li = tid; li < 40 * 34; li += 256) {
        int row = li / 34, c4 = li - row * 34;
        int col = c4 * 4;
        int gr = r0 - 4 + row;
        float4 z = make_float4(0.f, 0.f, 0.f, 0.f);
        if (gr >= 0 && gr < 128 && c4 >= 1 && c4 <= 32) {
            int gc = col - 4;
            ushort4 hv = *(const ushort4*)(hp + gr * 128 + gc);
            z = make_float4(fmaf(bf2f(hv.x), sc, sh), fmaf(bf2f(hv.y), sc, sh),
                            fmaf(bf2f(hv.z), sc, sh), fmaf(bf2f(hv.w), sc, sh));
        }
        *(float4*)&tile[row * 136 + col] = z;
    }
    __syncthreads();
    int r4g = tid >> 5, c4g = tid & 31;
    int orow0 = r4g * 4, oc0 = c4g * 4;
    const float* wch = w2e + ch * 81;
    float acc[4][4];
#pragma unroll
    for (int r = 0; r < 4; ++r)
#pragma unroll
        for (int k = 0; k < 4; ++k) acc[r][k] = 0.f;
#pragma unroll
    for (int d = 0; d < 12; ++d) {
        const float* lr = &tile[(orow0 + d) * 136 + oc0];
        float v[12];
        *(float4*)&v[0] = *(const float4*)lr;
        *(float4*)&v[4] = *(const float4*)(lr + 4);
        *(float4*)&v[8] = *(const float4*)(lr + 8);
#pragma unroll
        for (int r = 0; r < 4; ++r) {
            if (r <= d && d - r <= 8) {
                const int i = d - r;
#pragma unroll
                for (int j = 0; j < 9; ++j) {
                    float wv = wch[i * 9 + j];
                    acc[r][0] = fmaf(v[j + 0], wv, acc[r][0]);
                    acc[r][1] = fmaf(v[j + 1], wv, acc[r][1]);
                    acc[r][2] = fmaf(v[j + 2], wv, acc[r][2]);
                    acc[r][3] = fmaf(v[j + 3], wv, acc[r][3]);
                }
            }
        }
    }
    float s = 0.f, ss = 0.f;
    unsigned short* tpb = t + b * cHW + ch * HW + (r0 + orow0) * 128 + oc0;
#pragma unroll
    for (int r = 0; r < 4; ++r) {
        unsigned short* tp = tpb + r * 128;
        ushort4 tv = *(const ushort4*)tp;
        float r0v = bf2f(tv.x) + acc[r][0];
        float r1v = bf2f(tv.y) + acc[r][1];
        float r2v = bf2f(tv.z) + acc[r][2];
        float r3v = bf2f(tv.w) + acc[r][3];
        *(ushort4*)tp = make_ushort4(f2bf(r0v), f2bf(r1v), f2bf(r2v), f2bf(r3v));
        s += r0v + r1v + r2v + r3v;
        ss += r0v * r0v + r1v * r1v + r2v * r2v + r3v * r3v;
    }
#pragma unroll
    for (int off = 32; off; off >>= 1) { s += __shfl_xor(s, off, 64); ss += __shfl_xor(ss, off, 64); }
    __shared__ float rs[4], rss[4];
    int lane = tid & 63, wv2 = tid >> 6;
    if (lane == 0) { rs[wv2] = s; rss[wv2] = ss; }
    __syncthreads();
    if (tid == 0) {
        int gi = (b * 16 + (ch >> 2)) * 2;
        atomicAdd(&gnsa[gi], rs[0] + rs[1] + rs[2] + rs[3]);
        atomicAdd(&gnsa[gi + 1], rss[0] + rss[1] + rss[2] + rss[3]);
    }
}

// ---------------------------------------------------------------------------
// K6: conv2 (1x1, 64->256) via bf16 MFMA ; relu(GN_s) fused ; raw out bf16 ;
//     GN2 sums
// ---------------------------------------------------------------------------
__global__ __launch_bounds__(256) void k_conv2(const unsigned short* __restrict__ t,
        const float* __restrict__ scs, const float* __restrict__ shs,
        const unsigned short* __restrict__ w2p, const float* __restrict__ b2,
        unsigned short* __restrict__ raw, float* __restrict__ gn2a) {
    int bid = blockIdx.x;
    int obk = bid & 1, pt = (bid >> 1) & 127, b = bid >> 8;
    int tid = threadIdx.x;
    int w = tid >> 6, lane = tid & 63;
    int l15 = lane & 15, lg = lane >> 4;
    int pw = w >> 1, ow = w & 1;
    int p_wave = pt * 128 + pw * 64;
    __shared__ float lsc[64], lsh[64];
    __shared__ float red[4][4][2];
    if (tid < 64) { lsc[tid] = scs[b * 64 + tid]; lsh[tid] = shs[b * 64 + tid]; }
    __syncthreads();
    const bf16x8* w2v = (const bf16x8*)w2p;
    f32x4 acc[4][4];
#pragma unroll
    for (int mf = 0; mf < 4; ++mf)
#pragma unroll
        for (int nf = 0; nf < 4; ++nf) acc[mf][nf] = (f32x4){0.f, 0.f, 0.f, 0.f};
    const unsigned short* tb = t + b * cHW;
#pragma unroll
    for (int ks = 0; ks < 2; ++ks) {
        int kb = ks * 32 + lg * 8;
        float kc[8], kh[8];
#pragma unroll
        for (int j = 0; j < 8; ++j) { kc[j] = lsc[kb + j]; kh[j] = lsh[kb + j]; }
        bf16x8 afr[4];
#pragma unroll
        for (int mf = 0; mf < 4; ++mf) {
            const unsigned short* tp = tb + kb * HW + p_wave + mf * 16 + l15;
            bf16x8 a;
#pragma unroll
            for (int j = 0; j < 8; ++j) {
                float v = fmaxf(fmaf(bf2f(tp[j * HW]), kc[j], kh[j]), 0.f);
                a[j] = (short)f2bf(v);
            }
            afr[mf] = a;
        }
#pragma unroll
        for (int nf = 0; nf < 4; ++nf) {
            int fi = ks * 16 + (obk * 8 + ow * 4 + nf);
            bf16x8 bfr = w2v[fi * 64 + lane];
#pragma unroll
            for (int mf = 0; mf < 4; ++mf)
                acc[mf][nf] = __builtin_amdgcn_mfma_f32_16x16x32_bf16(afr[mf], bfr, acc[mf][nf], 0, 0, 0);
        }
    }
    int oc0 = obk * 128 + ow * 64;
    unsigned short* ob = raw + b * CHW;
    float sred[4], ssred[4];
#pragma unroll
    for (int nf = 0; nf < 4; ++nf) {
        int oc = oc0 + nf * 16 + l15;
        float bias = b2[oc];
        float s = 0.f, ss = 0.f;
#pragma unroll
        for (int mf = 0; mf < 4; ++mf) {
            f32x4 v = acc[mf][nf];
            v[0] += bias; v[1] += bias; v[2] += bias; v[3] += bias;
            ushort4 hv = make_ushort4(f2bf(v[0]), f2bf(v[1]), f2bf(v[2]), f2bf(v[3]));
            *(ushort4*)(ob + oc * HW + p_wave + mf * 16 + lg * 4) = hv;
            s += v[0] + v[1] + v[2] + v[3];
            ss += v[0] * v[0] + v[1] * v[1] + v[2] * v[2] + v[3] * v[3];
        }
#pragma unroll
        for (int off = 32; off; off >>= 1) { s += __shfl_xor(s, off, 64); ss += __shfl_xor(ss, off, 64); }
        sred[nf] = s; ssred[nf] = ss;
    }
    if (lane == 0) {
#pragma unroll
        for (int nf = 0; nf < 4; ++nf) { red[w][nf][0] = sred[nf]; red[w][nf][1] = ssred[nf]; }
    }
    __syncthreads();
    if (tid < 16) {
        int ow2 = tid >> 3, nf = (tid >> 1) & 3, c = tid & 1;
        float v = red[ow2][nf][c] + red[ow2 + 2][nf][c];
        int g = obk * 8 + ow2 * 4 + nf;
        atomicAdd(&gn2a[(b * 16 + g) * 2 + c], v);
    }
}

// ---------------------------------------------------------------------------
// K8: out = relu(GN2(raw)) + x   (raw bf16, 16 elems/iter, nt ext-vector IO)
// ---------------------------------------------------------------------------
__global__ __launch_bounds__(256) void k_final(const float* __restrict__ x,
        const unsigned short* __restrict__ raw,
        const float* __restrict__ sc2, const float* __restrict__ sh2,
        float* __restrict__ out) {
    int tid = blockIdx.x * blockDim.x + threadIdx.x;
    const int total16 = (BB * CHW) / 16;
    int stride = gridDim.x * blockDim.x;
    for (int i = tid; i < total16; i += stride) {
        int e = i * 16;
        int b = e >> 22;
        int o = (e >> 14) & 255;
        float s = sc2[b * 256 + o], h = sh2[b * 256 + o];
        u16x8 rv0 = ((const u16x8*)raw)[2 * i];
        u16x8 rv1 = ((const u16x8*)raw)[2 * i + 1];
        const f32x4* xp = (const f32x4*)x + 4 * i;
        f32x4 x0 = __builtin_nontemporal_load(xp);
        f32x4 x1 = __builtin_nontemporal_load(xp + 1);
        f32x4 x2 = __builtin_nontemporal_load(xp + 2);
        f32x4 x3 = __builtin_nontemporal_load(xp + 3);
        f32x4 r0, r1, r2, r3;
        r0[0] = fmaxf(fmaf(bf2f(rv0[0]), s, h), 0.f) + x0[0];
        r0[1] = fmaxf(fmaf(bf2f(rv0[1]), s, h), 0.f) + x0[1];
        r0[2] = fmaxf(fmaf(bf2f(rv0[2]), s, h), 0.f) + x0[2];
        r0[3] = fmaxf(fmaf(bf2f(rv0[3]), s, h), 0.f) + x0[3];
        r1[0] = fmaxf(fmaf(bf2f(rv0[4]), s, h), 0.f) + x1[0];
        r1[1] = fmaxf(fmaf(bf2f(rv0[5]), s, h), 0.f) + x1[1];
        r1[2] = fmaxf(fmaf(bf2f(rv0[6]), s, h), 0.f) + x1[2];
        r1[3] = fmaxf(fmaf(bf2f(rv0[7]), s, h), 0.f) + x1[3];
        r2[0] = fmaxf(fmaf(bf2f(rv1[0]), s, h), 0.f) + x2[0];
        r2[1] = fmaxf(fmaf(bf2f(rv1[1]), s, h), 0.f) + x2[1];
        r2[2] = fmaxf(fmaf(bf2f(rv1[2]), s, h), 0.f) + x2[2];
        r2[3] = fmaxf(fmaf(bf2f(rv1[3]), s, h), 0.f) + x2[3];
        r3[0] = fmaxf(fmaf(bf2f(rv1[4]), s, h), 0.f) + x3[0];
        r3[1] = fmaxf(fmaf(bf2f(rv1[5]), s, h), 0.f) + x3[1];
        r3[2] = fmaxf(fmaf(bf2f(rv1[6]), s, h), 0.f) + x3[2];
        r3[3] = fmaxf(fmaf(bf2f(rv1[7]), s, h), 0.f) + x3[3];
        f32x4* op = (f32x4*)out + 4 * i;
        __builtin_nontemporal_store(r0, op);
        __builtin_nontemporal_store(r1, op + 1);
        __builtin_nontemporal_store(r2, op + 2);
        __builtin_nontemporal_store(r3, op + 3);
    }
}

// ---------------------------------------------------------------------------
extern "C" void kernel_launch(void* const* d_in, const int* in_sizes, int n_in,
                              void* d_out, int out_size, void* d_ws, size_t ws_size,
                              hipStream_t stream) {
    (void)in_sizes; (void)n_in; (void)out_size; (void)ws_size;
    const float* x   = (const float*)d_in[0];
    const float* W1  = (const float*)d_in[1];
    const float* W2  = (const float*)d_in[2];
    const float* c1w = (const float*)d_in[3];
    const float* c1b = (const float*)d_in[4];
    const float* c2w = (const float*)d_in[5];
    const float* c2b = (const float*)d_in[6];
    const float* g1w = (const float*)d_in[7];
    const float* g1b = (const float*)d_in[8];
    const float* gsw = (const float*)d_in[9];
    const float* gsb = (const float*)d_in[10];
    const float* g2w = (const float*)d_in[11];
    const float* g2b = (const float*)d_in[12];
    float* out = (float*)d_out;
    float* ws  = (float*)d_ws;

    unsigned short* tb   = (unsigned short*)(ws + WS_TB);
    unsigned short* h1b  = (unsigned short*)(ws + WS_H1B);
    unsigned short* rawb = (unsigned short*)(ws + WS_RAWB);
    float* w2e  = ws + WS_W2E;
    float* k1e  = ws + WS_K1E;
    float* gn1a = ws + WS_GN1A;
    float* gnsa = ws + WS_GNSA;
    float* gn2a = ws + WS_GN2A;
    float* sc1  = ws + WS_SC1;
    float* sh1  = ws + WS_SH1;
    float* scs  = ws + WS_SCS;
    float* shs  = ws + WS_SHS;
    float* sc2  = ws + WS_SC2;
    float* sh2  = ws + WS_SH2;
    unsigned short* w1p = (unsigned short*)(ws + WS_W1P);
    unsigned short* w2p = (unsigned short*)(ws + WS_W2P);

    k_setup<<<1, 128, 0, stream>>>(W1, W2, c1w, c2w, k1e, w2e, gn1a, w1p, w2p);
    k_conv1<<<1024, 256, 0, stream>>>(x, w1p, c1b, h1b, gn1a);
    k_gnfin<<<4, 256, 0, stream>>>(gn1a, g1w, g1b, sc1, sh1, 1024, 6, 2, 1.f / 65536.f);
    k_x3<<<256, 256, 0, stream>>>(h1b, sc1, sh1, k1e, tb);
    k_xsa<<<4096, 256, 0, stream>>>(h1b, sc1, sh1, w2e, tb, gnsa);
    k_gnfin<<<4, 256, 0, stream>>>(gnsa, gsw, gsb, scs, shs, 1024, 6, 2, 1.f / 65536.f);
    k_conv2<<<4096, 256, 0, stream>>>(tb, scs, shs, w2p, c2b, rawb, gn2a);
    k_gnfin<<<16, 256, 0, stream>>>(gn2a, g2w, g2b, sc2, sh2, 4096, 8, 4, 1.f / 262144.f);
    k_final<<<4096, 256, 0, stream>>>(x, rawb, sc2, sh2, out);
}

// Round 8
// 374.101 us; speedup vs baseline: 1.2848x; 1.2848x over previous
//
#include <hip/hip_runtime.h>
#include <math.h>

// Problem constants
#define HW   16384        // 128*128
#define CC   256
#define cC   64
#define BB   16
#define CHW  (CC*HW)      // 4194304
#define cHW  (cC*HW)      // 1048576

// ws float offsets (ws_size = 1 GiB)
#define WS_TB    0                      // t bf16
#define WS_H1B   8388608                // h1 bf16
#define WS_RAWB  16777216               // conv2 raw bf16
#define WS_W2E   50331648
#define WS_K1E   (WS_W2E + 5184)
#define WS_GN1A  (WS_K1E + 16)
#define WS_GNSA  (WS_GN1A + 512)
#define WS_GN2A  (WS_GNSA + 512)
#define WS_SC1   (WS_GN2A + 512)
#define WS_SH1   (WS_SC1 + 1024)
#define WS_SCS   (WS_SH1 + 1024)
#define WS_SHS   (WS_SCS + 1024)
#define WS_SC2   (WS_SHS + 1024)
#define WS_SH2   (WS_SC2 + 4096)
#define WS_W1P   (WS_SH2 + 4096)
#define WS_W2P   (WS_W1P + 8192)

typedef __attribute__((ext_vector_type(8))) short bf16x8;
typedef __attribute__((ext_vector_type(4))) float f32x4;
typedef __attribute__((ext_vector_type(8))) unsigned short u16x8;

__device__ inline unsigned short f2bf(float f) {
    union { float f; unsigned u; } c; c.f = f;
    unsigned r = c.u + 0x7FFFu + ((c.u >> 16) & 1u);
    return (unsigned short)(r >> 16);
}
__device__ inline float bf2f(unsigned short h) {
    union { unsigned u; float f; } c; c.u = ((unsigned)h) << 16; return c.f;
}

// ---------------------------------------------------------------------------
// K0: effective kernels; zero GN accum; pack conv weights into MFMA frag order
// ---------------------------------------------------------------------------
__global__ void k_setup(const float* __restrict__ W1, const float* __restrict__ W2,
                        const float* __restrict__ c1w, const float* __restrict__ c2w,
                        float* __restrict__ k1e, float* __restrict__ w2e,
                        float* __restrict__ accz, unsigned short* __restrict__ w1p,
                        unsigned short* __restrict__ w2p) {
    __shared__ float tapsum[81];
    __shared__ float a2s[4];
    int tdx = threadIdx.x;
    for (int i = tdx; i < 1536; i += 128) accz[i] = 0.f;
    for (int e = tdx; e < 16384; e += 128) {
        int fi = e >> 9, rem = e & 511;
        int l = rem >> 3, j = rem & 7;
        int ks = fi >> 2, nf = fi & 3;
        int c = ks * 32 + (l >> 4) * 8 + j;
        int oc = nf * 16 + (l & 15);
        w1p[e] = f2bf(c1w[oc * 256 + c]);
    }
    for (int e = tdx; e < 16384; e += 128) {
        int fi = e >> 9, rem = e & 511;
        int l = rem >> 3, j = rem & 7;
        int ks = fi >> 4, nfg = fi & 15;
        int c = ks * 32 + (l >> 4) * 8 + j;
        int oc = nfg * 16 + (l & 15);
        w2p[e] = f2bf(c2w[oc * 64 + c]);
    }
    if (tdx < 81) {
        float s = 0.f;
        for (int ch = 0; ch < 64; ++ch) s += W2[ch * 81 + tdx];
        tapsum[tdx] = s;
    }
    __syncthreads();
    if (tdx == 0) {
        float ring[4] = {0.f, 0.f, 0.f, 0.f};
        for (int i = 0; i < 9; ++i)
            for (int j = 0; j < 9; ++j) {
                int d = max(abs(i - 4), abs(j - 4));
                int r = (d <= 1) ? 0 : (d - 1);
                ring[r] += tapsum[i * 9 + j];
            }
        float den2[4] = {576.f, 1024.f, 1536.f, 2048.f};
        float v[4], mx = -1e30f;
        for (int p = 0; p < 4; ++p) { v[p] = ring[p] / den2[p]; mx = fmaxf(mx, v[p]); }
        float se = 0.f;
        for (int p = 0; p < 4; ++p) { v[p] = expf(v[p] - mx); se += v[p]; }
        for (int p = 0; p < 4; ++p) a2s[p] = v[p] / se;
        float k1[9];
        for (int k = 0; k < 9; ++k) k1[k] = W1[k];
        float num[4];
        num[0] = k1[3] + k1[4] + k1[5];
        num[1] = k1[2] + k1[6];
        num[2] = k1[1] + k1[7];
        num[3] = k1[0] + k1[8];
        float den1[4] = {3.f, 2.f, 2.f, 2.f};
        mx = -1e30f;
        for (int p = 0; p < 4; ++p) { v[p] = num[p] / den1[p]; mx = fmaxf(mx, v[p]); }
        se = 0.f;
        for (int p = 0; p < 4; ++p) { v[p] = expf(v[p] - mx); se += v[p]; }
        float a1[4];
        for (int p = 0; p < 4; ++p) a1[p] = v[p] / se;
        float s1arr[5];
        s1arr[0] = 1.f; s1arr[1] = 1.f;
        s1arr[4] = a1[3]; s1arr[3] = a1[2] + a1[3]; s1arr[2] = a1[1] + s1arr[3];
        for (int k = 0; k < 9; ++k) { int d = abs(k - 4); k1e[k] = k1[k] * s1arr[d]; }
    }
    __syncthreads();
    float s2arr[5];
    s2arr[0] = 1.f; s2arr[1] = 1.f;
    s2arr[4] = a2s[3]; s2arr[3] = a2s[2] + a2s[3]; s2arr[2] = a2s[1] + s2arr[3];
    for (int idx = tdx; idx < 64 * 81; idx += 128) {
        int tap = idx % 81;
        int i = tap / 9, j = tap - i * 9;
        int d = max(abs(i - 4), abs(j - 4));
        w2e[idx] = W2[idx] * s2arr[d];
    }
}

// ---------------------------------------------------------------------------
// K1: conv1 (1x1, 256->64) via bf16 MFMA -> h1 bf16 [ch][p] ; GN1 sums
// ---------------------------------------------------------------------------
__global__ __launch_bounds__(256) void k_conv1(const float* __restrict__ x,
        const unsigned short* __restrict__ w1p, const float* __restrict__ b1,
        unsigned short* __restrict__ h1, float* __restrict__ gn1a) {
    int bid = blockIdx.x;
    int b = bid >> 6, pt = bid & 63;
    int tid = threadIdx.x;
    int w = tid >> 6, lane = tid & 63;
    int l15 = lane & 15, lg = lane >> 4;
    int p_wave = pt * 256 + w * 64;
    const bf16x8* w1v = (const bf16x8*)w1p;
    f32x4 acc[4][4];
#pragma unroll
    for (int mf = 0; mf < 4; ++mf)
#pragma unroll
        for (int nf = 0; nf < 4; ++nf) acc[mf][nf] = (f32x4){0.f, 0.f, 0.f, 0.f};
    const float* xb = x + b * CHW;
#pragma unroll 1
    for (int ks = 0; ks < 8; ++ks) {
        int c0 = ks * 32 + lg * 8;
        bf16x8 afr[4];
#pragma unroll
        for (int mf = 0; mf < 4; ++mf) {
            const float* xp = xb + c0 * HW + p_wave + mf * 16 + l15;
            bf16x8 a;
#pragma unroll
            for (int j = 0; j < 8; ++j) a[j] = (short)f2bf(__builtin_nontemporal_load(xp + j * HW));
            afr[mf] = a;
        }
#pragma unroll
        for (int nf = 0; nf < 4; ++nf) {
            bf16x8 bfr = w1v[(ks * 4 + nf) * 64 + lane];
#pragma unroll
            for (int mf = 0; mf < 4; ++mf)
                acc[mf][nf] = __builtin_amdgcn_mfma_f32_16x16x32_bf16(afr[mf], bfr, acc[mf][nf], 0, 0, 0);
        }
    }
    __shared__ float red[4][16][2];
    unsigned short* hb = h1 + b * cHW;
#pragma unroll
    for (int nf = 0; nf < 4; ++nf) {
        int oc = nf * 16 + l15;
        float bias = b1[oc];
        float s = 0.f, ss = 0.f;
#pragma unroll
        for (int mf = 0; mf < 4; ++mf) {
            f32x4 v = acc[mf][nf];
            v[0] += bias; v[1] += bias; v[2] += bias; v[3] += bias;
            ushort4 hv = make_ushort4(f2bf(v[0]), f2bf(v[1]), f2bf(v[2]), f2bf(v[3]));
            *(ushort4*)(hb + oc * HW + p_wave + mf * 16 + lg * 4) = hv;
            s += v[0] + v[1] + v[2] + v[3];
            ss += v[0] * v[0] + v[1] * v[1] + v[2] * v[2] + v[3] * v[3];
        }
        s += __shfl_xor(s, 16, 64); ss += __shfl_xor(ss, 16, 64);
        s += __shfl_xor(s, 32, 64); ss += __shfl_xor(ss, 32, 64);
        s += __shfl_xor(s, 1, 64);  ss += __shfl_xor(ss, 1, 64);
        s += __shfl_xor(s, 2, 64);  ss += __shfl_xor(ss, 2, 64);
        if (lg == 0 && (l15 & 3) == 0) {
            int g = nf * 4 + (l15 >> 2);
            red[w][g][0] = s; red[w][g][1] = ss;
        }
    }
    __syncthreads();
    if (tid < 32) {
        int g = tid >> 1, c = tid & 1;
        float v = red[0][g][c] + red[1][g][c] + red[2][g][c] + red[3][g][c];
        atomicAdd(&gn1a[(b * 16 + g) * 2 + c], v);
    }
}

// ---------------------------------------------------------------------------
// GN finalize
// ---------------------------------------------------------------------------
__global__ void k_gnfin(const float* __restrict__ accum, const float* __restrict__ gw,
                        const float* __restrict__ gb, float* __restrict__ scale,
                        float* __restrict__ shift, int nent, int chbits, int gshift,
                        float inv_n) {
    int idx = blockIdx.x * blockDim.x + threadIdx.x;
    if (idx >= nent) return;
    int chm = (1 << chbits) - 1;
    int ch = idx & chm, b = idx >> chbits, g = ch >> gshift;
    float s = accum[(b * 16 + g) * 2], ss = accum[(b * 16 + g) * 2 + 1];
    float mu = s * inv_n;
    float var = ss * inv_n - mu * mu;
    float rstd = rsqrtf(var + 1e-5f);
    float sc = gw[ch] * rstd;
    scale[idx] = sc;
    shift[idx] = gb[ch] - mu * sc;
}

// ---------------------------------------------------------------------------
// K3: channel-dim 9-tap conv (pad 4) -> t (bf16) ; 4 positions/thread
// ---------------------------------------------------------------------------
__global__ __launch_bounds__(256) void k_x3(const unsigned short* __restrict__ h1,
        const float* __restrict__ scale1, const float* __restrict__ shift1,
        const float* __restrict__ k1e, unsigned short* __restrict__ t) {
    int i = blockIdx.x * 256 + threadIdx.x;     // 0..65535
    int b = i >> 12, p = (i & 4095) * 4;
    __shared__ float lsc[64], lsh[64], lke[9];
    if (threadIdx.x < 64) {
        lsc[threadIdx.x] = scale1[b * 64 + threadIdx.x];
        lsh[threadIdx.x] = shift1[b * 64 + threadIdx.x];
    }
    if (threadIdx.x < 9) lke[threadIdx.x] = k1e[threadIdx.x];
    __syncthreads();
    const unsigned short* hb = h1 + b * cHW + p;
    float4 win[9];
#pragma unroll
    for (int k = 0; k < 9; ++k) {
        int ch = k - 4;
        if (ch >= 0) {
            ushort4 hv = *(const ushort4*)(hb + ch * HW);
            float s = lsc[ch], h = lsh[ch];
            win[k] = make_float4(fmaf(bf2f(hv.x), s, h), fmaf(bf2f(hv.y), s, h),
                                 fmaf(bf2f(hv.z), s, h), fmaf(bf2f(hv.w), s, h));
        } else win[k] = make_float4(0.f, 0.f, 0.f, 0.f);
    }
    unsigned short* tb = t + b * cHW + p;
#pragma unroll
    for (int ch = 0; ch < 64; ++ch) {
        float4 s = make_float4(0.f, 0.f, 0.f, 0.f);
#pragma unroll
        for (int k = 0; k < 9; ++k) {
            float kv = lke[k];
            s.x = fmaf(win[k].x, kv, s.x);
            s.y = fmaf(win[k].y, kv, s.y);
            s.z = fmaf(win[k].z, kv, s.z);
            s.w = fmaf(win[k].w, kv, s.w);
        }
        *(ushort4*)(tb + ch * HW) = make_ushort4(f2bf(s.x), f2bf(s.y), f2bf(s.z), f2bf(s.w));
#pragma unroll
        for (int k = 0; k < 8; ++k) win[k] = win[k + 1];
        int nc = ch + 5;
        if (nc < 64) {
            ushort4 hv = *(const ushort4*)(hb + nc * HW);
            float sN = lsc[nc], hN = lsh[nc];
            win[8] = make_float4(fmaf(bf2f(hv.x), sN, hN), fmaf(bf2f(hv.y), sN, hN),
                                 fmaf(bf2f(hv.z), sN, hN), fmaf(bf2f(hv.w), sN, hN));
        } else win[8] = make_float4(0.f, 0.f, 0.f, 0.f);
    }
}

// ---------------------------------------------------------------------------
// K4: depthwise 9x9 spatial conv ; t += x_sa (bf16 RMW) ; GN_s sums
// block = (b, ch, 32-row tile) ; thread = 4 rows x 4 cols ; tile 40x136 f32
// ---------------------------------------------------------------------------
__global__ __launch_bounds__(256) void k_xsa(const unsigned short* __restrict__ h1,
        const float* __restrict__ scale1, const float* __restrict__ shift1,
        const float* __restrict__ w2e, unsigned short* __restrict__ t,
        float* __restrict__ gnsa) {
    int bid = blockIdx.x;
    int b = bid >> 8, ch = (bid >> 2) & 63, rt = bid & 3;
    int r0 = rt * 32;
    int tid = threadIdx.x;
    const float sc = scale1[b * 64 + ch];
    const float sh = shift1[b * 64 + ch];
    const unsigned short* hp = h1 + b * cHW + ch * HW;
    __shared__ float tile[40 * 136];            // 21.25 KB
    for (int li = tid; li < 40 * 34; li += 256) {
        int row = li / 34, c4 = li - row * 34;
        int col = c4 * 4;
        int gr = r0 - 4 + row;
        float4 z = make_float4(0.f, 0.f, 0.f, 0.f);
        if (gr >= 0 && gr < 128 && c4 >= 1 && c4 <= 32) {
            int gc = col - 4;
            ushort4 hv = *(const ushort4*)(hp + gr * 128 + gc);
            z = make_float4(fmaf(bf2f(hv.x), sc, sh), fmaf(bf2f(hv.y), sc, sh),
                            fmaf(bf2f(hv.z), sc, sh), fmaf(bf2f(hv.w), sc, sh));
        }
        *(float4*)&tile[row * 136 + col] = z;
    }
    __syncthreads();
    int r4g = tid >> 5, c4g = tid & 31;
    int orow0 = r4g * 4, oc0 = c4g * 4;
    const float* wch = w2e + ch * 81;
    float acc[4][4];
#pragma unroll
    for (int r = 0; r < 4; ++r)
#pragma unroll
        for (int k = 0; k < 4; ++k) acc[r][k] = 0.f;
#pragma unroll
    for (int d = 0; d < 12; ++d) {
        const float* lr = &tile[(orow0 + d) * 136 + oc0];
        float v[12];
        *(float4*)&v[0] = *(const float4*)lr;
        *(float4*)&v[4] = *(const float4*)(lr + 4);
        *(float4*)&v[8] = *(const float4*)(lr + 8);
#pragma unroll
        for (int r = 0; r < 4; ++r) {
            if (r <= d && d - r <= 8) {
                const int i = d - r;
#pragma unroll
                for (int j = 0; j < 9; ++j) {
                    float wv = wch[i * 9 + j];
                    acc[r][0] = fmaf(v[j + 0], wv, acc[r][0]);
                    acc[r][1] = fmaf(v[j + 1], wv, acc[r][1]);
                    acc[r][2] = fmaf(v[j + 2], wv, acc[r][2]);
                    acc[r][3] = fmaf(v[j + 3], wv, acc[r][3]);
                }
            }
        }
    }
    float s = 0.f, ss = 0.f;
    unsigned short* tpb = t + b * cHW + ch * HW + (r0 + orow0) * 128 + oc0;
#pragma unroll
    for (int r = 0; r < 4; ++r) {
        unsigned short* tp = tpb + r * 128;
        ushort4 tv = *(const ushort4*)tp;
        float r0v = bf2f(tv.x) + acc[r][0];
        float r1v = bf2f(tv.y) + acc[r][1];
        float r2v = bf2f(tv.z) + acc[r][2];
        float r3v = bf2f(tv.w) + acc[r][3];
        *(ushort4*)tp = make_ushort4(f2bf(r0v), f2bf(r1v), f2bf(r2v), f2bf(r3v));
        s += r0v + r1v + r2v + r3v;
        ss += r0v * r0v + r1v * r1v + r2v * r2v + r3v * r3v;
    }
#pragma unroll
    for (int off = 32; off; off >>= 1) { s += __shfl_xor(s, off, 64); ss += __shfl_xor(ss, off, 64); }
    __shared__ float rs[4], rss[4];
    int lane = tid & 63, wv2 = tid >> 6;
    if (lane == 0) { rs[wv2] = s; rss[wv2] = ss; }
    __syncthreads();
    if (tid == 0) {
        int gi = (b * 16 + (ch >> 2)) * 2;
        atomicAdd(&gnsa[gi], rs[0] + rs[1] + rs[2] + rs[3]);
        atomicAdd(&gnsa[gi + 1], rss[0] + rss[1] + rss[2] + rss[3]);
    }
}

// ---------------------------------------------------------------------------
// K6: conv2 (1x1, 64->256) via bf16 MFMA ; relu(GN_s) fused ; raw out bf16 ;
//     GN2 sums
// ---------------------------------------------------------------------------
__global__ __launch_bounds__(256) void k_conv2(const unsigned short* __restrict__ t,
        const float* __restrict__ scs, const float* __restrict__ shs,
        const unsigned short* __restrict__ w2p, const float* __restrict__ b2,
        unsigned short* __restrict__ raw, float* __restrict__ gn2a) {
    int bid = blockIdx.x;
    int obk = bid & 1, pt = (bid >> 1) & 127, b = bid >> 8;
    int tid = threadIdx.x;
    int w = tid >> 6, lane = tid & 63;
    int l15 = lane & 15, lg = lane >> 4;
    int pw = w >> 1, ow = w & 1;
    int p_wave = pt * 128 + pw * 64;
    __shared__ float lsc[64], lsh[64];
    __shared__ float red[4][4][2];
    if (tid < 64) { lsc[tid] = scs[b * 64 + tid]; lsh[tid] = shs[b * 64 + tid]; }
    __syncthreads();
    const bf16x8* w2v = (const bf16x8*)w2p;
    f32x4 acc[4][4];
#pragma unroll
    for (int mf = 0; mf < 4; ++mf)
#pragma unroll
        for (int nf = 0; nf < 4; ++nf) acc[mf][nf] = (f32x4){0.f, 0.f, 0.f, 0.f};
    const unsigned short* tb = t + b * cHW;
#pragma unroll
    for (int ks = 0; ks < 2; ++ks) {
        int kb = ks * 32 + lg * 8;
        float kc[8], kh[8];
#pragma unroll
        for (int j = 0; j < 8; ++j) { kc[j] = lsc[kb + j]; kh[j] = lsh[kb + j]; }
        bf16x8 afr[4];
#pragma unroll
        for (int mf = 0; mf < 4; ++mf) {
            const unsigned short* tp = tb + kb * HW + p_wave + mf * 16 + l15;
            bf16x8 a;
#pragma unroll
            for (int j = 0; j < 8; ++j) {
                float v = fmaxf(fmaf(bf2f(tp[j * HW]), kc[j], kh[j]), 0.f);
                a[j] = (short)f2bf(v);
            }
            afr[mf] = a;
        }
#pragma unroll
        for (int nf = 0; nf < 4; ++nf) {
            int fi = ks * 16 + (obk * 8 + ow * 4 + nf);
            bf16x8 bfr = w2v[fi * 64 + lane];
#pragma unroll
            for (int mf = 0; mf < 4; ++mf)
                acc[mf][nf] = __builtin_amdgcn_mfma_f32_16x16x32_bf16(afr[mf], bfr, acc[mf][nf], 0, 0, 0);
        }
    }
    int oc0 = obk * 128 + ow * 64;
    unsigned short* ob = raw + b * CHW;
    float sred[4], ssred[4];
#pragma unroll
    for (int nf = 0; nf < 4; ++nf) {
        int oc = oc0 + nf * 16 + l15;
        float bias = b2[oc];
        float s = 0.f, ss = 0.f;
#pragma unroll
        for (int mf = 0; mf < 4; ++mf) {
            f32x4 v = acc[mf][nf];
            v[0] += bias; v[1] += bias; v[2] += bias; v[3] += bias;
            ushort4 hv = make_ushort4(f2bf(v[0]), f2bf(v[1]), f2bf(v[2]), f2bf(v[3]));
            *(ushort4*)(ob + oc * HW + p_wave + mf * 16 + lg * 4) = hv;
            s += v[0] + v[1] + v[2] + v[3];
            ss += v[0] * v[0] + v[1] * v[1] + v[2] * v[2] + v[3] * v[3];
        }
#pragma unroll
        for (int off = 32; off; off >>= 1) { s += __shfl_xor(s, off, 64); ss += __shfl_xor(ss, off, 64); }
        sred[nf] = s; ssred[nf] = ss;
    }
    if (lane == 0) {
#pragma unroll
        for (int nf = 0; nf < 4; ++nf) { red[w][nf][0] = sred[nf]; red[w][nf][1] = ssred[nf]; }
    }
    __syncthreads();
    if (tid < 16) {
        int ow2 = tid >> 3, nf = (tid >> 1) & 3, c = tid & 1;
        float v = red[ow2][nf][c] + red[ow2 + 2][nf][c];
        int g = obk * 8 + ow2 * 4 + nf;
        atomicAdd(&gn2a[(b * 16 + g) * 2 + c], v);
    }
}

// ---------------------------------------------------------------------------
// K8: out = relu(GN2(raw)) + x ; 4 elems/thread, fully coalesced,
//     nt loads for x only, regular stores (L2-merged full lines)
// ---------------------------------------------------------------------------
__global__ __launch_bounds__(256) void k_final(const float* __restrict__ x,
        const unsigned short* __restrict__ raw,
        const float* __restrict__ sc2, const float* __restrict__ sh2,
        float* __restrict__ out) {
    int tid = blockIdx.x * blockDim.x + threadIdx.x;
    const int total4 = (BB * CHW) / 4;
    int stride = gridDim.x * blockDim.x;
    for (int i = tid; i < total4; i += stride) {
        int e = i * 4;
        int b = e >> 22;
        int o = (e >> 14) & 255;
        float s = sc2[b * 256 + o], h = sh2[b * 256 + o];
        ushort4 rv = ((const ushort4*)raw)[i];
        f32x4 xv = __builtin_nontemporal_load((const f32x4*)x + i);
        f32x4 r;
        r[0] = fmaxf(fmaf(bf2f(rv.x), s, h), 0.f) + xv[0];
        r[1] = fmaxf(fmaf(bf2f(rv.y), s, h), 0.f) + xv[1];
        r[2] = fmaxf(fmaf(bf2f(rv.z), s, h), 0.f) + xv[2];
        r[3] = fmaxf(fmaf(bf2f(rv.w), s, h), 0.f) + xv[3];
        ((f32x4*)out)[i] = r;
    }
}

// ---------------------------------------------------------------------------
extern "C" void kernel_launch(void* const* d_in, const int* in_sizes, int n_in,
                              void* d_out, int out_size, void* d_ws, size_t ws_size,
                              hipStream_t stream) {
    (void)in_sizes; (void)n_in; (void)out_size; (void)ws_size;
    const float* x   = (const float*)d_in[0];
    const float* W1  = (const float*)d_in[1];
    const float* W2  = (const float*)d_in[2];
    const float* c1w = (const float*)d_in[3];
    const float* c1b = (const float*)d_in[4];
    const float* c2w = (const float*)d_in[5];
    const float* c2b = (const float*)d_in[6];
    const float* g1w = (const float*)d_in[7];
    const float* g1b = (const float*)d_in[8];
    const float* gsw = (const float*)d_in[9];
    const float* gsb = (const float*)d_in[10];
    const float* g2w = (const float*)d_in[11];
    const float* g2b = (const float*)d_in[12];
    float* out = (float*)d_out;
    float* ws  = (float*)d_ws;

    unsigned short* tb   = (unsigned short*)(ws + WS_TB);
    unsigned short* h1b  = (unsigned short*)(ws + WS_H1B);
    unsigned short* rawb = (unsigned short*)(ws + WS_RAWB);
    float* w2e  = ws + WS_W2E;
    float* k1e  = ws + WS_K1E;
    float* gn1a = ws + WS_GN1A;
    float* gnsa = ws + WS_GNSA;
    float* gn2a = ws + WS_GN2A;
    float* sc1  = ws + WS_SC1;
    float* sh1  = ws + WS_SH1;
    float* scs  = ws + WS_SCS;
    float* shs  = ws + WS_SHS;
    float* sc2  = ws + WS_SC2;
    float* sh2  = ws + WS_SH2;
    unsigned short* w1p = (unsigned short*)(ws + WS_W1P);
    unsigned short* w2p = (unsigned short*)(ws + WS_W2P);

    k_setup<<<1, 128, 0, stream>>>(W1, W2, c1w, c2w, k1e, w2e, gn1a, w1p, w2p);
    k_conv1<<<1024, 256, 0, stream>>>(x, w1p, c1b, h1b, gn1a);
    k_gnfin<<<4, 256, 0, stream>>>(gn1a, g1w, g1b, sc1, sh1, 1024, 6, 2, 1.f / 65536.f);
    k_x3<<<256, 256, 0, stream>>>(h1b, sc1, sh1, k1e, tb);
    k_xsa<<<4096, 256, 0, stream>>>(h1b, sc1, sh1, w2e, tb, gnsa);
    k_gnfin<<<4, 256, 0, stream>>>(gnsa, gsw, gsb, scs, shs, 1024, 6, 2, 1.f / 65536.f);
    k_conv2<<<4096, 256, 0, stream>>>(tb, scs, shs, w2p, c2b, rawb, gn2a);
    k_gnfin<<<16, 256, 0, stream>>>(gn2a, g2w, g2b, sc2, sh2, 4096, 8, 4, 1.f / 262144.f);
    k_final<<<4096, 256, 0, stream>>>(x, rawb, sc2, sh2, out);
}

// Round 9
// 350.480 us; speedup vs baseline: 1.3714x; 1.0674x over previous
//
#include <hip/hip_runtime.h>
#include <math.h>

// Problem constants
#define HW   16384        // 128*128
#define CC   256
#define cC   64
#define BB   16
#define CHW  (CC*HW)      // 4194304
#define cHW  (cC*HW)      // 1048576

// ws float offsets (ws_size = 1 GiB)
#define WS_TB    0                      // t bf16
#define WS_H1B   8388608                // h1 bf16
#define WS_RAWB  16777216               // conv2 raw bf16
#define WS_W2E   50331648
#define WS_K1E   (WS_W2E + 5184)
#define WS_GN1A  (WS_K1E + 16)
#define WS_GNSA  (WS_GN1A + 512)
#define WS_GN2A  (WS_GNSA + 512)
#define WS_SC1   (WS_GN2A + 512)
#define WS_SH1   (WS_SC1 + 1024)
#define WS_SCS   (WS_SH1 + 1024)
#define WS_SHS   (WS_SCS + 1024)
#define WS_SC2   (WS_SHS + 1024)
#define WS_SH2   (WS_SC2 + 4096)
#define WS_W1P   (WS_SH2 + 4096)
#define WS_W2P   (WS_W1P + 8192)

typedef __attribute__((ext_vector_type(8))) short bf16x8;
typedef __attribute__((ext_vector_type(4))) float f32x4;

__device__ inline unsigned short f2bf(float f) {
    union { float f; unsigned u; } c; c.f = f;
    unsigned r = c.u + 0x7FFFu + ((c.u >> 16) & 1u);
    return (unsigned short)(r >> 16);
}
__device__ inline float bf2f(unsigned short h) {
    union { unsigned u; float f; } c; c.u = ((unsigned)h) << 16; return c.f;
}

// ---------------------------------------------------------------------------
// K0: effective kernels; zero GN accum; pack conv weights into MFMA frag order
// ---------------------------------------------------------------------------
__global__ void k_setup(const float* __restrict__ W1, const float* __restrict__ W2,
                        const float* __restrict__ c1w, const float* __restrict__ c2w,
                        float* __restrict__ k1e, float* __restrict__ w2e,
                        float* __restrict__ accz, unsigned short* __restrict__ w1p,
                        unsigned short* __restrict__ w2p) {
    __shared__ float tapsum[81];
    __shared__ float a2s[4];
    int tdx = threadIdx.x;
    for (int i = tdx; i < 1536; i += 128) accz[i] = 0.f;
    for (int e = tdx; e < 16384; e += 128) {
        int fi = e >> 9, rem = e & 511;
        int l = rem >> 3, j = rem & 7;
        int ks = fi >> 2, nf = fi & 3;
        int c = ks * 32 + (l >> 4) * 8 + j;
        int oc = nf * 16 + (l & 15);
        w1p[e] = f2bf(c1w[oc * 256 + c]);
    }
    for (int e = tdx; e < 16384; e += 128) {
        int fi = e >> 9, rem = e & 511;
        int l = rem >> 3, j = rem & 7;
        int ks = fi >> 4, nfg = fi & 15;
        int c = ks * 32 + (l >> 4) * 8 + j;
        int oc = nfg * 16 + (l & 15);
        w2p[e] = f2bf(c2w[oc * 64 + c]);
    }
    if (tdx < 81) {
        float s = 0.f;
        for (int ch = 0; ch < 64; ++ch) s += W2[ch * 81 + tdx];
        tapsum[tdx] = s;
    }
    __syncthreads();
    if (tdx == 0) {
        float ring[4] = {0.f, 0.f, 0.f, 0.f};
        for (int i = 0; i < 9; ++i)
            for (int j = 0; j < 9; ++j) {
                int d = max(abs(i - 4), abs(j - 4));
                int r = (d <= 1) ? 0 : (d - 1);
                ring[r] += tapsum[i * 9 + j];
            }
        float den2[4] = {576.f, 1024.f, 1536.f, 2048.f};
        float v[4], mx = -1e30f;
        for (int p = 0; p < 4; ++p) { v[p] = ring[p] / den2[p]; mx = fmaxf(mx, v[p]); }
        float se = 0.f;
        for (int p = 0; p < 4; ++p) { v[p] = expf(v[p] - mx); se += v[p]; }
        for (int p = 0; p < 4; ++p) a2s[p] = v[p] / se;
        float k1[9];
        for (int k = 0; k < 9; ++k) k1[k] = W1[k];
        float num[4];
        num[0] = k1[3] + k1[4] + k1[5];
        num[1] = k1[2] + k1[6];
        num[2] = k1[1] + k1[7];
        num[3] = k1[0] + k1[8];
        float den1[4] = {3.f, 2.f, 2.f, 2.f};
        mx = -1e30f;
        for (int p = 0; p < 4; ++p) { v[p] = num[p] / den1[p]; mx = fmaxf(mx, v[p]); }
        se = 0.f;
        for (int p = 0; p < 4; ++p) { v[p] = expf(v[p] - mx); se += v[p]; }
        float a1[4];
        for (int p = 0; p < 4; ++p) a1[p] = v[p] / se;
        float s1arr[5];
        s1arr[0] = 1.f; s1arr[1] = 1.f;
        s1arr[4] = a1[3]; s1arr[3] = a1[2] + a1[3]; s1arr[2] = a1[1] + s1arr[3];
        for (int k = 0; k < 9; ++k) { int d = abs(k - 4); k1e[k] = k1[k] * s1arr[d]; }
    }
    __syncthreads();
    float s2arr[5];
    s2arr[0] = 1.f; s2arr[1] = 1.f;
    s2arr[4] = a2s[3]; s2arr[3] = a2s[2] + a2s[3]; s2arr[2] = a2s[1] + s2arr[3];
    for (int idx = tdx; idx < 64 * 81; idx += 128) {
        int tap = idx % 81;
        int i = tap / 9, j = tap - i * 9;
        int d = max(abs(i - 4), abs(j - 4));
        w2e[idx] = W2[idx] * s2arr[d];
    }
}

// ---------------------------------------------------------------------------
// K1: conv1 (1x1, 256->64) via bf16 MFMA -> h1 bf16 [ch][p] ; GN1 sums
// ---------------------------------------------------------------------------
__global__ __launch_bounds__(256) void k_conv1(const float* __restrict__ x,
        const unsigned short* __restrict__ w1p, const float* __restrict__ b1,
        unsigned short* __restrict__ h1, float* __restrict__ gn1a) {
    int bid = blockIdx.x;
    int b = bid >> 6, pt = bid & 63;
    int tid = threadIdx.x;
    int w = tid >> 6, lane = tid & 63;
    int l15 = lane & 15, lg = lane >> 4;
    int p_wave = pt * 256 + w * 64;
    const bf16x8* w1v = (const bf16x8*)w1p;
    f32x4 acc[4][4];
#pragma unroll
    for (int mf = 0; mf < 4; ++mf)
#pragma unroll
        for (int nf = 0; nf < 4; ++nf) acc[mf][nf] = (f32x4){0.f, 0.f, 0.f, 0.f};
    const float* xb = x + b * CHW;
#pragma unroll 1
    for (int ks = 0; ks < 8; ++ks) {
        int c0 = ks * 32 + lg * 8;
        bf16x8 afr[4];
#pragma unroll
        for (int mf = 0; mf < 4; ++mf) {
            const float* xp = xb + c0 * HW + p_wave + mf * 16 + l15;
            bf16x8 a;
#pragma unroll
            for (int j = 0; j < 8; ++j) a[j] = (short)f2bf(__builtin_nontemporal_load(xp + j * HW));
            afr[mf] = a;
        }
#pragma unroll
        for (int nf = 0; nf < 4; ++nf) {
            bf16x8 bfr = w1v[(ks * 4 + nf) * 64 + lane];
#pragma unroll
            for (int mf = 0; mf < 4; ++mf)
                acc[mf][nf] = __builtin_amdgcn_mfma_f32_16x16x32_bf16(afr[mf], bfr, acc[mf][nf], 0, 0, 0);
        }
    }
    __shared__ float red[4][16][2];
    unsigned short* hb = h1 + b * cHW;
#pragma unroll
    for (int nf = 0; nf < 4; ++nf) {
        int oc = nf * 16 + l15;
        float bias = b1[oc];
        float s = 0.f, ss = 0.f;
#pragma unroll
        for (int mf = 0; mf < 4; ++mf) {
            f32x4 v = acc[mf][nf];
            v[0] += bias; v[1] += bias; v[2] += bias; v[3] += bias;
            ushort4 hv = make_ushort4(f2bf(v[0]), f2bf(v[1]), f2bf(v[2]), f2bf(v[3]));
            *(ushort4*)(hb + oc * HW + p_wave + mf * 16 + lg * 4) = hv;
            s += v[0] + v[1] + v[2] + v[3];
            ss += v[0] * v[0] + v[1] * v[1] + v[2] * v[2] + v[3] * v[3];
        }
        s += __shfl_xor(s, 16, 64); ss += __shfl_xor(ss, 16, 64);
        s += __shfl_xor(s, 32, 64); ss += __shfl_xor(ss, 32, 64);
        s += __shfl_xor(s, 1, 64);  ss += __shfl_xor(ss, 1, 64);
        s += __shfl_xor(s, 2, 64);  ss += __shfl_xor(ss, 2, 64);
        if (lg == 0 && (l15 & 3) == 0) {
            int g = nf * 4 + (l15 >> 2);
            red[w][g][0] = s; red[w][g][1] = ss;
        }
    }
    __syncthreads();
    if (tid < 32) {
        int g = tid >> 1, c = tid & 1;
        float v = red[0][g][c] + red[1][g][c] + red[2][g][c] + red[3][g][c];
        atomicAdd(&gn1a[(b * 16 + g) * 2 + c], v);
    }
}

// ---------------------------------------------------------------------------
// GN finalize
// ---------------------------------------------------------------------------
__global__ void k_gnfin(const float* __restrict__ accum, const float* __restrict__ gw,
                        const float* __restrict__ gb, float* __restrict__ scale,
                        float* __restrict__ shift, int nent, int chbits, int gshift,
                        float inv_n) {
    int idx = blockIdx.x * blockDim.x + threadIdx.x;
    if (idx >= nent) return;
    int chm = (1 << chbits) - 1;
    int ch = idx & chm, b = idx >> chbits, g = ch >> gshift;
    float s = accum[(b * 16 + g) * 2], ss = accum[(b * 16 + g) * 2 + 1];
    float mu = s * inv_n;
    float var = ss * inv_n - mu * mu;
    float rstd = rsqrtf(var + 1e-5f);
    float sc = gw[ch] * rstd;
    scale[idx] = sc;
    shift[idx] = gb[ch] - mu * sc;
}

// ---------------------------------------------------------------------------
// K3: channel-dim 9-tap conv (pad 4) -> t (bf16) ; 2 positions/thread,
//     512 blocks (2 waves/SIMD for latency hiding)
// ---------------------------------------------------------------------------
__global__ __launch_bounds__(256) void k_x3(const unsigned short* __restrict__ h1,
        const float* __restrict__ scale1, const float* __restrict__ shift1,
        const float* __restrict__ k1e, unsigned short* __restrict__ t) {
    int i = blockIdx.x * 256 + threadIdx.x;     // 0..131071
    int b = i >> 13, p = (i & 8191) * 2;
    __shared__ float lsc[64], lsh[64], lke[9];
    if (threadIdx.x < 64) {
        lsc[threadIdx.x] = scale1[b * 64 + threadIdx.x];
        lsh[threadIdx.x] = shift1[b * 64 + threadIdx.x];
    }
    if (threadIdx.x < 9) lke[threadIdx.x] = k1e[threadIdx.x];
    __syncthreads();
    const unsigned short* hb = h1 + b * cHW + p;
    float2 win[9];
#pragma unroll
    for (int k = 0; k < 9; ++k) {
        int ch = k - 4;
        if (ch >= 0) {
            ushort2 hv = *(const ushort2*)(hb + ch * HW);
            float s = lsc[ch], h = lsh[ch];
            win[k] = make_float2(fmaf(bf2f(hv.x), s, h), fmaf(bf2f(hv.y), s, h));
        } else win[k] = make_float2(0.f, 0.f);
    }
    unsigned short* tb = t + b * cHW + p;
#pragma unroll
    for (int ch = 0; ch < 64; ++ch) {
        float2 s = make_float2(0.f, 0.f);
#pragma unroll
        for (int k = 0; k < 9; ++k) {
            float kv = lke[k];
            s.x = fmaf(win[k].x, kv, s.x);
            s.y = fmaf(win[k].y, kv, s.y);
        }
        *(ushort2*)(tb + ch * HW) = make_ushort2(f2bf(s.x), f2bf(s.y));
#pragma unroll
        for (int k = 0; k < 8; ++k) win[k] = win[k + 1];
        int nc = ch + 5;
        if (nc < 64) {
            ushort2 hv = *(const ushort2*)(hb + nc * HW);
            float sN = lsc[nc], hN = lsh[nc];
            win[8] = make_float2(fmaf(bf2f(hv.x), sN, hN), fmaf(bf2f(hv.y), sN, hN));
        } else win[8] = make_float2(0.f, 0.f);
    }
}

// ---------------------------------------------------------------------------
// K4: depthwise 9x9 spatial conv ; t += x_sa (bf16 RMW) ; GN_s sums
// block = (b, ch, 32-row tile) ; thread = 4 rows x 4 cols ; tile 40x136 f32
// ---------------------------------------------------------------------------
__global__ __launch_bounds__(256) void k_xsa(const unsigned short* __restrict__ h1,
        const float* __restrict__ scale1, const float* __restrict__ shift1,
        const float* __restrict__ w2e, unsigned short* __restrict__ t,
        float* __restrict__ gnsa) {
    int bid = blockIdx.x;
    int b = bid >> 8, ch = (bid >> 2) & 63, rt = bid & 3;
    int r0 = rt * 32;
    int tid = threadIdx.x;
    const float sc = scale1[b * 64 + ch];
    const float sh = shift1[b * 64 + ch];
    const unsigned short* hp = h1 + b * cHW + ch * HW;
    __shared__ float tile[40 * 136];            // 21.25 KB
    for (int li = tid; li < 40 * 34; li += 256) {
        int row = li / 34, c4 = li - row * 34;
        int col = c4 * 4;
        int gr = r0 - 4 + row;
        float4 z = make_float4(0.f, 0.f, 0.f, 0.f);
        if (gr >= 0 && gr < 128 && c4 >= 1 && c4 <= 32) {
            int gc = col - 4;
            ushort4 hv = *(const ushort4*)(hp + gr * 128 + gc);
            z = make_float4(fmaf(bf2f(hv.x), sc, sh), fmaf(bf2f(hv.y), sc, sh),
                            fmaf(bf2f(hv.z), sc, sh), fmaf(bf2f(hv.w), sc, sh));
        }
        *(float4*)&tile[row * 136 + col] = z;
    }
    __syncthreads();
    int r4g = tid >> 5, c4g = tid & 31;
    int orow0 = r4g * 4, oc0 = c4g * 4;
    const float* wch = w2e + ch * 81;
    float acc[4][4];
#pragma unroll
    for (int r = 0; r < 4; ++r)
#pragma unroll
        for (int k = 0; k < 4; ++k) acc[r][k] = 0.f;
#pragma unroll
    for (int d = 0; d < 12; ++d) {
        const float* lr = &tile[(orow0 + d) * 136 + oc0];
        float v[12];
        *(float4*)&v[0] = *(const float4*)lr;
        *(float4*)&v[4] = *(const float4*)(lr + 4);
        *(float4*)&v[8] = *(const float4*)(lr + 8);
#pragma unroll
        for (int r = 0; r < 4; ++r) {
            if (r <= d && d - r <= 8) {
                const int i = d - r;
#pragma unroll
                for (int j = 0; j < 9; ++j) {
                    float wv = wch[i * 9 + j];
                    acc[r][0] = fmaf(v[j + 0], wv, acc[r][0]);
                    acc[r][1] = fmaf(v[j + 1], wv, acc[r][1]);
                    acc[r][2] = fmaf(v[j + 2], wv, acc[r][2]);
                    acc[r][3] = fmaf(v[j + 3], wv, acc[r][3]);
                }
            }
        }
    }
    float s = 0.f, ss = 0.f;
    unsigned short* tpb = t + b * cHW + ch * HW + (r0 + orow0) * 128 + oc0;
#pragma unroll
    for (int r = 0; r < 4; ++r) {
        unsigned short* tp = tpb + r * 128;
        ushort4 tv = *(const ushort4*)tp;
        float r0v = bf2f(tv.x) + acc[r][0];
        float r1v = bf2f(tv.y) + acc[r][1];
        float r2v = bf2f(tv.z) + acc[r][2];
        float r3v = bf2f(tv.w) + acc[r][3];
        *(ushort4*)tp = make_ushort4(f2bf(r0v), f2bf(r1v), f2bf(r2v), f2bf(r3v));
        s += r0v + r1v + r2v + r3v;
        ss += r0v * r0v + r1v * r1v + r2v * r2v + r3v * r3v;
    }
#pragma unroll
    for (int off = 32; off; off >>= 1) { s += __shfl_xor(s, off, 64); ss += __shfl_xor(ss, off, 64); }
    __shared__ float rs[4], rss[4];
    int lane = tid & 63, wv2 = tid >> 6;
    if (lane == 0) { rs[wv2] = s; rss[wv2] = ss; }
    __syncthreads();
    if (tid == 0) {
        int gi = (b * 16 + (ch >> 2)) * 2;
        atomicAdd(&gnsa[gi], rs[0] + rs[1] + rs[2] + rs[3]);
        atomicAdd(&gnsa[gi + 1], rss[0] + rss[1] + rss[2] + rss[3]);
    }
}

// ---------------------------------------------------------------------------
// K6: conv2 (1x1, 64->256) via bf16 MFMA ; relu(GN_s) fused ; raw out bf16 ;
//     GN2 sums
// ---------------------------------------------------------------------------
__global__ __launch_bounds__(256) void k_conv2(const unsigned short* __restrict__ t,
        const float* __restrict__ scs, const float* __restrict__ shs,
        const unsigned short* __restrict__ w2p, const float* __restrict__ b2,
        unsigned short* __restrict__ raw, float* __restrict__ gn2a) {
    int bid = blockIdx.x;
    int obk = bid & 1, pt = (bid >> 1) & 127, b = bid >> 8;
    int tid = threadIdx.x;
    int w = tid >> 6, lane = tid & 63;
    int l15 = lane & 15, lg = lane >> 4;
    int pw = w >> 1, ow = w & 1;
    int p_wave = pt * 128 + pw * 64;
    __shared__ float lsc[64], lsh[64];
    __shared__ float red[4][4][2];
    if (tid < 64) { lsc[tid] = scs[b * 64 + tid]; lsh[tid] = shs[b * 64 + tid]; }
    __syncthreads();
    const bf16x8* w2v = (const bf16x8*)w2p;
    f32x4 acc[4][4];
#pragma unroll
    for (int mf = 0; mf < 4; ++mf)
#pragma unroll
        for (int nf = 0; nf < 4; ++nf) acc[mf][nf] = (f32x4){0.f, 0.f, 0.f, 0.f};
    const unsigned short* tb = t + b * cHW;
#pragma unroll
    for (int ks = 0; ks < 2; ++ks) {
        int kb = ks * 32 + lg * 8;
        float kc[8], kh[8];
#pragma unroll
        for (int j = 0; j < 8; ++j) { kc[j] = lsc[kb + j]; kh[j] = lsh[kb + j]; }
        bf16x8 afr[4];
#pragma unroll
        for (int mf = 0; mf < 4; ++mf) {
            const unsigned short* tp = tb + kb * HW + p_wave + mf * 16 + l15;
            bf16x8 a;
#pragma unroll
            for (int j = 0; j < 8; ++j) {
                float v = fmaxf(fmaf(bf2f(tp[j * HW]), kc[j], kh[j]), 0.f);
                a[j] = (short)f2bf(v);
            }
            afr[mf] = a;
        }
#pragma unroll
        for (int nf = 0; nf < 4; ++nf) {
            int fi = ks * 16 + (obk * 8 + ow * 4 + nf);
            bf16x8 bfr = w2v[fi * 64 + lane];
#pragma unroll
            for (int mf = 0; mf < 4; ++mf)
                acc[mf][nf] = __builtin_amdgcn_mfma_f32_16x16x32_bf16(afr[mf], bfr, acc[mf][nf], 0, 0, 0);
        }
    }
    int oc0 = obk * 128 + ow * 64;
    unsigned short* ob = raw + b * CHW;
    float sred[4], ssred[4];
#pragma unroll
    for (int nf = 0; nf < 4; ++nf) {
        int oc = oc0 + nf * 16 + l15;
        float bias = b2[oc];
        float s = 0.f, ss = 0.f;
#pragma unroll
        for (int mf = 0; mf < 4; ++mf) {
            f32x4 v = acc[mf][nf];
            v[0] += bias; v[1] += bias; v[2] += bias; v[3] += bias;
            ushort4 hv = make_ushort4(f2bf(v[0]), f2bf(v[1]), f2bf(v[2]), f2bf(v[3]));
            *(ushort4*)(ob + oc * HW + p_wave + mf * 16 + lg * 4) = hv;
            s += v[0] + v[1] + v[2] + v[3];
            ss += v[0] * v[0] + v[1] * v[1] + v[2] * v[2] + v[3] * v[3];
        }
#pragma unroll
        for (int off = 32; off; off >>= 1) { s += __shfl_xor(s, off, 64); ss += __shfl_xor(ss, off, 64); }
        sred[nf] = s; ssred[nf] = ss;
    }
    if (lane == 0) {
#pragma unroll
        for (int nf = 0; nf < 4; ++nf) { red[w][nf][0] = sred[nf]; red[w][nf][1] = ssred[nf]; }
    }
    __syncthreads();
    if (tid < 16) {
        int ow2 = tid >> 3, nf = (tid >> 1) & 3, c = tid & 1;
        float v = red[ow2][nf][c] + red[ow2 + 2][nf][c];
        int g = obk * 8 + ow2 * 4 + nf;
        atomicAdd(&gn2a[(b * 16 + g) * 2 + c], v);
    }
}

// ---------------------------------------------------------------------------
// K8: out = relu(GN2(raw)) + x ; 4 elems/thread, fully coalesced,
//     nt loads for x, nt stores for out (full-line, no L2/L3 pollution)
// ---------------------------------------------------------------------------
__global__ __launch_bounds__(256) void k_final(const float* __restrict__ x,
        const unsigned short* __restrict__ raw,
        const float* __restrict__ sc2, const float* __restrict__ sh2,
        float* __restrict__ out) {
    int tid = blockIdx.x * blockDim.x + threadIdx.x;
    const int total4 = (BB * CHW) / 4;
    int stride = gridDim.x * blockDim.x;
    for (int i = tid; i < total4; i += stride) {
        int e = i * 4;
        int b = e >> 22;
        int o = (e >> 14) & 255;
        float s = sc2[b * 256 + o], h = sh2[b * 256 + o];
        ushort4 rv = ((const ushort4*)raw)[i];
        f32x4 xv = __builtin_nontemporal_load((const f32x4*)x + i);
        f32x4 r;
        r[0] = fmaxf(fmaf(bf2f(rv.x), s, h), 0.f) + xv[0];
        r[1] = fmaxf(fmaf(bf2f(rv.y), s, h), 0.f) + xv[1];
        r[2] = fmaxf(fmaf(bf2f(rv.z), s, h), 0.f) + xv[2];
        r[3] = fmaxf(fmaf(bf2f(rv.w), s, h), 0.f) + xv[3];
        __builtin_nontemporal_store(r, (f32x4*)out + i);
    }
}

// ---------------------------------------------------------------------------
extern "C" void kernel_launch(void* const* d_in, const int* in_sizes, int n_in,
                              void* d_out, int out_size, void* d_ws, size_t ws_size,
                              hipStream_t stream) {
    (void)in_sizes; (void)n_in; (void)out_size; (void)ws_size;
    const float* x   = (const float*)d_in[0];
    const float* W1  = (const float*)d_in[1];
    const float* W2  = (const float*)d_in[2];
    const float* c1w = (const float*)d_in[3];
    const float* c1b = (const float*)d_in[4];
    const float* c2w = (const float*)d_in[5];
    const float* c2b = (const float*)d_in[6];
    const float* g1w = (const float*)d_in[7];
    const float* g1b = (const float*)d_in[8];
    const float* gsw = (const float*)d_in[9];
    const float* gsb = (const float*)d_in[10];
    const float* g2w = (const float*)d_in[11];
    const float* g2b = (const float*)d_in[12];
    float* out = (float*)d_out;
    float* ws  = (float*)d_ws;

    unsigned short* tb   = (unsigned short*)(ws + WS_TB);
    unsigned short* h1b  = (unsigned short*)(ws + WS_H1B);
    unsigned short* rawb = (unsigned short*)(ws + WS_RAWB);
    float* w2e  = ws + WS_W2E;
    float* k1e  = ws + WS_K1E;
    float* gn1a = ws + WS_GN1A;
    float* gnsa = ws + WS_GNSA;
    float* gn2a = ws + WS_GN2A;
    float* sc1  = ws + WS_SC1;
    float* sh1  = ws + WS_SH1;
    float* scs  = ws + WS_SCS;
    float* shs  = ws + WS_SHS;
    float* sc2  = ws + WS_SC2;
    float* sh2  = ws + WS_SH2;
    unsigned short* w1p = (unsigned short*)(ws + WS_W1P);
    unsigned short* w2p = (unsigned short*)(ws + WS_W2P);

    k_setup<<<1, 128, 0, stream>>>(W1, W2, c1w, c2w, k1e, w2e, gn1a, w1p, w2p);
    k_conv1<<<1024, 256, 0, stream>>>(x, w1p, c1b, h1b, gn1a);
    k_gnfin<<<4, 256, 0, stream>>>(gn1a, g1w, g1b, sc1, sh1, 1024, 6, 2, 1.f / 65536.f);
    k_x3<<<512, 256, 0, stream>>>(h1b, sc1, sh1, k1e, tb);
    k_xsa<<<4096, 256, 0, stream>>>(h1b, sc1, sh1, w2e, tb, gnsa);
    k_gnfin<<<4, 256, 0, stream>>>(gnsa, gsw, gsb, scs, shs, 1024, 6, 2, 1.f / 65536.f);
    k_conv2<<<4096, 256, 0, stream>>>(tb, scs, shs, w2p, c2b, rawb, gn2a);
    k_gnfin<<<16, 256, 0, stream>>>(gn2a, g2w, g2b, sc2, sh2, 4096, 8, 4, 1.f / 262144.f);
    k_final<<<4096, 256, 0, stream>>>(x, rawb, sc2, sh2, out);
}

// Round 11
// 344.658 us; speedup vs baseline: 1.3945x; 1.0169x over previous
//
#include <hip/hip_runtime.h>
#include <math.h>

// Problem constants
#define HW   16384        // 128*128
#define CC   256
#define cC   64
#define BB   16
#define CHW  (CC*HW)      // 4194304
#define cHW  (cC*HW)      // 1048576

// ws float offsets (ws_size = 1 GiB)
#define WS_TB    0                      // t bf16
#define WS_H1B   8388608                // h1 bf16
#define WS_RAWB  16777216               // conv2 raw bf16
#define WS_W2E   50331648
#define WS_K1E   (WS_W2E + 5184)
#define WS_GN1A  (WS_K1E + 16)
#define WS_GNSA  (WS_GN1A + 512)
#define WS_GN2A  (WS_GNSA + 512)
#define WS_W1P   (WS_GN2A + 512)
#define WS_W2P   (WS_W1P + 8192)

typedef __attribute__((ext_vector_type(8))) short bf16x8;
typedef __attribute__((ext_vector_type(4))) float f32x4;

__device__ inline unsigned short f2bf(float f) {
    union { float f; unsigned u; } c; c.f = f;
    unsigned r = c.u + 0x7FFFu + ((c.u >> 16) & 1u);
    return (unsigned short)(r >> 16);
}
__device__ inline float bf2f(unsigned short h) {
    union { unsigned u; float f; } c; c.u = ((unsigned)h) << 16; return c.f;
}

// ---------------------------------------------------------------------------
// K0: effective kernels; zero GN accum; pack conv weights into MFMA frag order
// ---------------------------------------------------------------------------
__global__ void k_setup(const float* __restrict__ W1, const float* __restrict__ W2,
                        const float* __restrict__ c1w, const float* __restrict__ c2w,
                        float* __restrict__ k1e, float* __restrict__ w2e,
                        float* __restrict__ accz, unsigned short* __restrict__ w1p,
                        unsigned short* __restrict__ w2p) {
    __shared__ float tapsum[81];
    __shared__ float a2s[4];
    int tdx = threadIdx.x;
    for (int i = tdx; i < 1536; i += 128) accz[i] = 0.f;
    for (int e = tdx; e < 16384; e += 128) {
        int fi = e >> 9, rem = e & 511;
        int l = rem >> 3, j = rem & 7;
        int ks = fi >> 2, nf = fi & 3;
        int c = ks * 32 + (l >> 4) * 8 + j;
        int oc = nf * 16 + (l & 15);
        w1p[e] = f2bf(c1w[oc * 256 + c]);
    }
    for (int e = tdx; e < 16384; e += 128) {
        int fi = e >> 9, rem = e & 511;
        int l = rem >> 3, j = rem & 7;
        int ks = fi >> 4, nfg = fi & 15;
        int c = ks * 32 + (l >> 4) * 8 + j;
        int oc = nfg * 16 + (l & 15);
        w2p[e] = f2bf(c2w[oc * 64 + c]);
    }
    if (tdx < 81) {
        float s = 0.f;
        for (int ch = 0; ch < 64; ++ch) s += W2[ch * 81 + tdx];
        tapsum[tdx] = s;
    }
    __syncthreads();
    if (tdx == 0) {
        float ring[4] = {0.f, 0.f, 0.f, 0.f};
        for (int i = 0; i < 9; ++i)
            for (int j = 0; j < 9; ++j) {
                int d = max(abs(i - 4), abs(j - 4));
                int r = (d <= 1) ? 0 : (d - 1);
                ring[r] += tapsum[i * 9 + j];
            }
        float den2[4] = {576.f, 1024.f, 1536.f, 2048.f};
        float v[4], mx = -1e30f;
        for (int p = 0; p < 4; ++p) { v[p] = ring[p] / den2[p]; mx = fmaxf(mx, v[p]); }
        float se = 0.f;
        for (int p = 0; p < 4; ++p) { v[p] = expf(v[p] - mx); se += v[p]; }
        for (int p = 0; p < 4; ++p) a2s[p] = v[p] / se;
        float k1[9];
        for (int k = 0; k < 9; ++k) k1[k] = W1[k];
        float num[4];
        num[0] = k1[3] + k1[4] + k1[5];
        num[1] = k1[2] + k1[6];
        num[2] = k1[1] + k1[7];
        num[3] = k1[0] + k1[8];
        float den1[4] = {3.f, 2.f, 2.f, 2.f};
        mx = -1e30f;
        for (int p = 0; p < 4; ++p) { v[p] = num[p] / den1[p]; mx = fmaxf(mx, v[p]); }
        se = 0.f;
        for (int p = 0; p < 4; ++p) { v[p] = expf(v[p] - mx); se += v[p]; }
        float a1[4];
        for (int p = 0; p < 4; ++p) a1[p] = v[p] / se;
        float s1arr[5];
        s1arr[0] = 1.f; s1arr[1] = 1.f;
        s1arr[4] = a1[3]; s1arr[3] = a1[2] + a1[3]; s1arr[2] = a1[1] + s1arr[3];
        for (int k = 0; k < 9; ++k) { int d = abs(k - 4); k1e[k] = k1[k] * s1arr[d]; }
    }
    __syncthreads();
    float s2arr[5];
    s2arr[0] = 1.f; s2arr[1] = 1.f;
    s2arr[4] = a2s[3]; s2arr[3] = a2s[2] + a2s[3]; s2arr[2] = a2s[1] + s2arr[3];
    for (int idx = tdx; idx < 64 * 81; idx += 128) {
        int tap = idx % 81;
        int i = tap / 9, j = tap - i * 9;
        int d = max(abs(i - 4), abs(j - 4));
        w2e[idx] = W2[idx] * s2arr[d];
    }
}

// ---------------------------------------------------------------------------
// GN affine helper: from accum pair -> scale/shift for channel ch
// ---------------------------------------------------------------------------
__device__ inline void gn_affine(const float* __restrict__ acc, int b, int g,
                                 float inv_n, const float* __restrict__ gw,
                                 const float* __restrict__ gb, int ch,
                                 float& sc, float& sh) {
    float s = acc[(b * 16 + g) * 2], ss = acc[(b * 16 + g) * 2 + 1];
    float mu = s * inv_n;
    float var = ss * inv_n - mu * mu;
    float rstd = rsqrtf(var + 1e-5f);
    sc = gw[ch] * rstd;
    sh = gb[ch] - mu * sc;
}

// ---------------------------------------------------------------------------
// K1: conv1 (1x1, 256->64) via bf16 MFMA -> h1 bf16 [ch][p] ; GN1 sums
// ---------------------------------------------------------------------------
__global__ __launch_bounds__(256) void k_conv1(const float* __restrict__ x,
        const unsigned short* __restrict__ w1p, const float* __restrict__ b1,
        unsigned short* __restrict__ h1, float* __restrict__ gn1a) {
    int bid = blockIdx.x;
    int b = bid >> 6, pt = bid & 63;
    int tid = threadIdx.x;
    int w = tid >> 6, lane = tid & 63;
    int l15 = lane & 15, lg = lane >> 4;
    int p_wave = pt * 256 + w * 64;
    const bf16x8* w1v = (const bf16x8*)w1p;
    f32x4 acc[4][4];
#pragma unroll
    for (int mf = 0; mf < 4; ++mf)
#pragma unroll
        for (int nf = 0; nf < 4; ++nf) acc[mf][nf] = (f32x4){0.f, 0.f, 0.f, 0.f};
    const float* xb = x + b * CHW;
#pragma unroll 1
    for (int ks = 0; ks < 8; ++ks) {
        int c0 = ks * 32 + lg * 8;
        bf16x8 afr[4];
#pragma unroll
        for (int mf = 0; mf < 4; ++mf) {
            const float* xp = xb + c0 * HW + p_wave + mf * 16 + l15;
            bf16x8 a;
#pragma unroll
            for (int j = 0; j < 8; ++j) a[j] = (short)f2bf(__builtin_nontemporal_load(xp + j * HW));
            afr[mf] = a;
        }
#pragma unroll
        for (int nf = 0; nf < 4; ++nf) {
            bf16x8 bfr = w1v[(ks * 4 + nf) * 64 + lane];
#pragma unroll
            for (int mf = 0; mf < 4; ++mf)
                acc[mf][nf] = __builtin_amdgcn_mfma_f32_16x16x32_bf16(afr[mf], bfr, acc[mf][nf], 0, 0, 0);
        }
    }
    __shared__ float red[4][16][2];
    unsigned short* hb = h1 + b * cHW;
#pragma unroll
    for (int nf = 0; nf < 4; ++nf) {
        int oc = nf * 16 + l15;
        float bias = b1[oc];
        float s = 0.f, ss = 0.f;
#pragma unroll
        for (int mf = 0; mf < 4; ++mf) {
            f32x4 v = acc[mf][nf];
            v[0] += bias; v[1] += bias; v[2] += bias; v[3] += bias;
            ushort4 hv = make_ushort4(f2bf(v[0]), f2bf(v[1]), f2bf(v[2]), f2bf(v[3]));
            *(ushort4*)(hb + oc * HW + p_wave + mf * 16 + lg * 4) = hv;
            s += v[0] + v[1] + v[2] + v[3];
            ss += v[0] * v[0] + v[1] * v[1] + v[2] * v[2] + v[3] * v[3];
        }
        s += __shfl_xor(s, 16, 64); ss += __shfl_xor(ss, 16, 64);
        s += __shfl_xor(s, 32, 64); ss += __shfl_xor(ss, 32, 64);
        s += __shfl_xor(s, 1, 64);  ss += __shfl_xor(ss, 1, 64);
        s += __shfl_xor(s, 2, 64);  ss += __shfl_xor(ss, 2, 64);
        if (lg == 0 && (l15 & 3) == 0) {
            int g = nf * 4 + (l15 >> 2);
            red[w][g][0] = s; red[w][g][1] = ss;
        }
    }
    __syncthreads();
    if (tid < 32) {
        int g = tid >> 1, c = tid & 1;
        float v = red[0][g][c] + red[1][g][c] + red[2][g][c] + red[3][g][c];
        atomicAdd(&gn1a[(b * 16 + g) * 2 + c], v);
    }
}

// ---------------------------------------------------------------------------
// K3: channel-dim 9-tap conv (pad 4) -> t (bf16) ; 2 positions/thread ;
//     GN1 affine computed inline from gn1a
// ---------------------------------------------------------------------------
__global__ __launch_bounds__(256) void k_x3(const unsigned short* __restrict__ h1,
        const float* __restrict__ gn1a, const float* __restrict__ g1w,
        const float* __restrict__ g1b, const float* __restrict__ k1e,
        unsigned short* __restrict__ t) {
    int i = blockIdx.x * 256 + threadIdx.x;     // 0..131071
    int b = i >> 13, p = (i & 8191) * 2;
    __shared__ float lsc[64], lsh[64], lke[9];
    if (threadIdx.x < 64) {
        int ch = threadIdx.x;
        float sc, sh;
        gn_affine(gn1a, b, ch >> 2, 1.f / 65536.f, g1w, g1b, ch, sc, sh);
        lsc[ch] = sc; lsh[ch] = sh;
    }
    if (threadIdx.x < 9) lke[threadIdx.x] = k1e[threadIdx.x];
    __syncthreads();
    const unsigned short* hb = h1 + b * cHW + p;
    float2 win[9];
#pragma unroll
    for (int k = 0; k < 9; ++k) {
        int ch = k - 4;
        if (ch >= 0) {
            ushort2 hv = *(const ushort2*)(hb + ch * HW);
            float s = lsc[ch], h = lsh[ch];
            win[k] = make_float2(fmaf(bf2f(hv.x), s, h), fmaf(bf2f(hv.y), s, h));
        } else win[k] = make_float2(0.f, 0.f);
    }
    unsigned short* tb = t + b * cHW + p;
#pragma unroll
    for (int ch = 0; ch < 64; ++ch) {
        float2 s = make_float2(0.f, 0.f);
#pragma unroll
        for (int k = 0; k < 9; ++k) {
            float kv = lke[k];
            s.x = fmaf(win[k].x, kv, s.x);
            s.y = fmaf(win[k].y, kv, s.y);
        }
        *(ushort2*)(tb + ch * HW) = make_ushort2(f2bf(s.x), f2bf(s.y));
#pragma unroll
        for (int k = 0; k < 8; ++k) win[k] = win[k + 1];
        int nc = ch + 5;
        if (nc < 64) {
            ushort2 hv = *(const ushort2*)(hb + nc * HW);
            float sN = lsc[nc], hN = lsh[nc];
            win[8] = make_float2(fmaf(bf2f(hv.x), sN, hN), fmaf(bf2f(hv.y), sN, hN));
        } else win[8] = make_float2(0.f, 0.f);
    }
}

// ---------------------------------------------------------------------------
// K4: depthwise 9x9 spatial conv ; t += x_sa (bf16 RMW) ; GN_s sums ;
//     GN1 affine (single channel) computed inline
// ---------------------------------------------------------------------------
__global__ __launch_bounds__(256) void k_xsa(const unsigned short* __restrict__ h1,
        const float* __restrict__ gn1a, const float* __restrict__ g1w,
        const float* __restrict__ g1b, const float* __restrict__ w2e,
        unsigned short* __restrict__ t, float* __restrict__ gnsa) {
    int bid = blockIdx.x;
    int b = bid >> 8, ch = (bid >> 2) & 63, rt = bid & 3;
    int r0 = rt * 32;
    int tid = threadIdx.x;
    float sc, sh;
    gn_affine(gn1a, b, ch >> 2, 1.f / 65536.f, g1w, g1b, ch, sc, sh);
    const unsigned short* hp = h1 + b * cHW + ch * HW;
    __shared__ float tile[40 * 136];            // 21.25 KB
    for (int li = tid; li < 40 * 34; li += 256) {
        int row = li / 34, c4 = li - row * 34;
        int col = c4 * 4;
        int gr = r0 - 4 + row;
        float4 z = make_float4(0.f, 0.f, 0.f, 0.f);
        if (gr >= 0 && gr < 128 && c4 >= 1 && c4 <= 32) {
            int gc = col - 4;
            ushort4 hv = *(const ushort4*)(hp + gr * 128 + gc);
            z = make_float4(fmaf(bf2f(hv.x), sc, sh), fmaf(bf2f(hv.y), sc, sh),
                            fmaf(bf2f(hv.z), sc, sh), fmaf(bf2f(hv.w), sc, sh));
        }
        *(float4*)&tile[row * 136 + col] = z;
    }
    __syncthreads();
    int r4g = tid >> 5, c4g = tid & 31;
    int orow0 = r4g * 4, oc0 = c4g * 4;
    const float* wch = w2e + ch * 81;
    float acc[4][4];
#pragma unroll
    for (int r = 0; r < 4; ++r)
#pragma unroll
        for (int k = 0; k < 4; ++k) acc[r][k] = 0.f;
#pragma unroll
    for (int d = 0; d < 12; ++d) {
        const float* lr = &tile[(orow0 + d) * 136 + oc0];
        float v[12];
        *(float4*)&v[0] = *(const float4*)lr;
        *(float4*)&v[4] = *(const float4*)(lr + 4);
        *(float4*)&v[8] = *(const float4*)(lr + 8);
#pragma unroll
        for (int r = 0; r < 4; ++r) {
            if (r <= d && d - r <= 8) {
                const int i = d - r;
#pragma unroll
                for (int j = 0; j < 9; ++j) {
                    float wv = wch[i * 9 + j];
                    acc[r][0] = fmaf(v[j + 0], wv, acc[r][0]);
                    acc[r][1] = fmaf(v[j + 1], wv, acc[r][1]);
                    acc[r][2] = fmaf(v[j + 2], wv, acc[r][2]);
                    acc[r][3] = fmaf(v[j + 3], wv, acc[r][3]);
                }
            }
        }
    }
    float s = 0.f, ss = 0.f;
    unsigned short* tpb = t + b * cHW + ch * HW + (r0 + orow0) * 128 + oc0;
#pragma unroll
    for (int r = 0; r < 4; ++r) {
        unsigned short* tp = tpb + r * 128;
        ushort4 tv = *(const ushort4*)tp;
        float r0v = bf2f(tv.x) + acc[r][0];
        float r1v = bf2f(tv.y) + acc[r][1];
        float r2v = bf2f(tv.z) + acc[r][2];
        float r3v = bf2f(tv.w) + acc[r][3];
        *(ushort4*)tp = make_ushort4(f2bf(r0v), f2bf(r1v), f2bf(r2v), f2bf(r3v));
        s += r0v + r1v + r2v + r3v;
        ss += r0v * r0v + r1v * r1v + r2v * r2v + r3v * r3v;
    }
#pragma unroll
    for (int off = 32; off; off >>= 1) { s += __shfl_xor(s, off, 64); ss += __shfl_xor(ss, off, 64); }
    __shared__ float rs[4], rss[4];
    int lane = tid & 63, wv2 = tid >> 6;
    if (lane == 0) { rs[wv2] = s; rss[wv2] = ss; }
    __syncthreads();
    if (tid == 0) {
        int gi = (b * 16 + (ch >> 2)) * 2;
        atomicAdd(&gnsa[gi], rs[0] + rs[1] + rs[2] + rs[3]);
        atomicAdd(&gnsa[gi + 1], rss[0] + rss[1] + rss[2] + rss[3]);
    }
}

// ---------------------------------------------------------------------------
// K6: conv2 (1x1, 64->256) via bf16 MFMA ; relu(GN_s) fused (inline affine) ;
//     raw out bf16 ; GN2 sums
// ---------------------------------------------------------------------------
__global__ __launch_bounds__(256) void k_conv2(const unsigned short* __restrict__ t,
        const float* __restrict__ gnsa, const float* __restrict__ gsw,
        const float* __restrict__ gsb, const unsigned short* __restrict__ w2p,
        const float* __restrict__ b2, unsigned short* __restrict__ raw,
        float* __restrict__ gn2a) {
    int bid = blockIdx.x;
    int obk = bid & 1, pt = (bid >> 1) & 127, b = bid >> 8;
    int tid = threadIdx.x;
    int w = tid >> 6, lane = tid & 63;
    int l15 = lane & 15, lg = lane >> 4;
    int pw = w >> 1, ow = w & 1;
    int p_wave = pt * 128 + pw * 64;
    __shared__ float lsc[64], lsh[64];
    __shared__ float red[4][4][2];
    if (tid < 64) {
        float sc, sh;
        gn_affine(gnsa, b, tid >> 2, 1.f / 65536.f, gsw, gsb, tid, sc, sh);
        lsc[tid] = sc; lsh[tid] = sh;
    }
    __syncthreads();
    const bf16x8* w2v = (const bf16x8*)w2p;
    f32x4 acc[4][4];
#pragma unroll
    for (int mf = 0; mf < 4; ++mf)
#pragma unroll
        for (int nf = 0; nf < 4; ++nf) acc[mf][nf] = (f32x4){0.f, 0.f, 0.f, 0.f};
    const unsigned short* tb = t + b * cHW;
#pragma unroll
    for (int ks = 0; ks < 2; ++ks) {
        int kb = ks * 32 + lg * 8;
        float kc[8], kh[8];
#pragma unroll
        for (int j = 0; j < 8; ++j) { kc[j] = lsc[kb + j]; kh[j] = lsh[kb + j]; }
        bf16x8 afr[4];
#pragma unroll
        for (int mf = 0; mf < 4; ++mf) {
            const unsigned short* tp = tb + kb * HW + p_wave + mf * 16 + l15;
            bf16x8 a;
#pragma unroll
            for (int j = 0; j < 8; ++j) {
                float v = fmaxf(fmaf(bf2f(tp[j * HW]), kc[j], kh[j]), 0.f);
                a[j] = (short)f2bf(v);
            }
            afr[mf] = a;
        }
#pragma unroll
        for (int nf = 0; nf < 4; ++nf) {
            int fi = ks * 16 + (obk * 8 + ow * 4 + nf);
            bf16x8 bfr = w2v[fi * 64 + lane];
#pragma unroll
            for (int mf = 0; mf < 4; ++mf)
                acc[mf][nf] = __builtin_amdgcn_mfma_f32_16x16x32_bf16(afr[mf], bfr, acc[mf][nf], 0, 0, 0);
        }
    }
    int oc0 = obk * 128 + ow * 64;
    unsigned short* ob = raw + b * CHW;
    float sred[4], ssred[4];
#pragma unroll
    for (int nf = 0; nf < 4; ++nf) {
        int oc = oc0 + nf * 16 + l15;
        float bias = b2[oc];
        float s = 0.f, ss = 0.f;
#pragma unroll
        for (int mf = 0; mf < 4; ++mf) {
            f32x4 v = acc[mf][nf];
            v[0] += bias; v[1] += bias; v[2] += bias; v[3] += bias;
            ushort4 hv = make_ushort4(f2bf(v[0]), f2bf(v[1]), f2bf(v[2]), f2bf(v[3]));
            *(ushort4*)(ob + oc * HW + p_wave + mf * 16 + lg * 4) = hv;
            s += v[0] + v[1] + v[2] + v[3];
            ss += v[0] * v[0] + v[1] * v[1] + v[2] * v[2] + v[3] * v[3];
        }
#pragma unroll
        for (int off = 32; off; off >>= 1) { s += __shfl_xor(s, off, 64); ss += __shfl_xor(ss, off, 64); }
        sred[nf] = s; ssred[nf] = ss;
    }
    if (lane == 0) {
#pragma unroll
        for (int nf = 0; nf < 4; ++nf) { red[w][nf][0] = sred[nf]; red[w][nf][1] = ssred[nf]; }
    }
    __syncthreads();
    if (tid < 16) {
        int ow2 = tid >> 3, nf = (tid >> 1) & 3, c = tid & 1;
        float v = red[ow2][nf][c] + red[ow2 + 2][nf][c];
        int g = obk * 8 + ow2 * 4 + nf;
        atomicAdd(&gn2a[(b * 16 + g) * 2 + c], v);
    }
}

// ---------------------------------------------------------------------------
// K8: out = relu(GN2(raw)) + x ; inline GN2 affine from gn2a ; coalesced 4/thread
// ---------------------------------------------------------------------------
__global__ __launch_bounds__(256) void k_final(const float* __restrict__ x,
        const unsigned short* __restrict__ raw, const float* __restrict__ gn2a,
        const float* __restrict__ g2w, const float* __restrict__ g2b,
        float* __restrict__ out) {
    int tid = blockIdx.x * blockDim.x + threadIdx.x;
    const int total4 = (BB * CHW) / 4;
    int stride = gridDim.x * blockDim.x;
    for (int i = tid; i < total4; i += stride) {
        int e = i * 4;
        int b = e >> 22;
        int o = (e >> 14) & 255;
        float s, h;
        gn_affine(gn2a, b, o >> 4, 1.f / 262144.f, g2w, g2b, o, s, h);
        ushort4 rv = ((const ushort4*)raw)[i];
        f32x4 xv = __builtin_nontemporal_load((const f32x4*)x + i);
        f32x4 r;
        r[0] = fmaxf(fmaf(bf2f(rv.x), s, h), 0.f) + xv[0];
        r[1] = fmaxf(fmaf(bf2f(rv.y), s, h), 0.f) + xv[1];
        r[2] = fmaxf(fmaf(bf2f(rv.z), s, h), 0.f) + xv[2];
        r[3] = fmaxf(fmaf(bf2f(rv.w), s, h), 0.f) + xv[3];
        __builtin_nontemporal_store(r, (f32x4*)out + i);
    }
}

// ---------------------------------------------------------------------------
extern "C" void kernel_launch(void* const* d_in, const int* in_sizes, int n_in,
                              void* d_out, int out_size, void* d_ws, size_t ws_size,
                              hipStream_t stream) {
    (void)in_sizes; (void)n_in; (void)out_size; (void)ws_size;
    const float* x   = (const float*)d_in[0];
    const float* W1  = (const float*)d_in[1];
    const float* W2  = (const float*)d_in[2];
    const float* c1w = (const float*)d_in[3];
    const float* c1b = (const float*)d_in[4];
    const float* c2w = (const float*)d_in[5];
    const float* c2b = (const float*)d_in[6];
    const float* g1w = (const float*)d_in[7];
    const float* g1b = (const float*)d_in[8];
    const float* gsw = (const float*)d_in[9];
    const float* gsb = (const float*)d_in[10];
    const float* g2w = (const float*)d_in[11];
    const float* g2b = (const float*)d_in[12];
    float* out = (float*)d_out;
    float* ws  = (float*)d_ws;

    unsigned short* tb   = (unsigned short*)(ws + WS_TB);
    unsigned short* h1b  = (unsigned short*)(ws + WS_H1B);
    unsigned short* rawb = (unsigned short*)(ws + WS_RAWB);
    float* w2e  = ws + WS_W2E;
    float* k1e  = ws + WS_K1E;
    float* gn1a = ws + WS_GN1A;
    float* gnsa = ws + WS_GNSA;
    float* gn2a = ws + WS_GN2A;
    unsigned short* w1p = (unsigned short*)(ws + WS_W1P);
    unsigned short* w2p = (unsigned short*)(ws + WS_W2P);

    k_setup<<<1, 128, 0, stream>>>(W1, W2, c1w, c2w, k1e, w2e, gn1a, w1p, w2p);
    k_conv1<<<1024, 256, 0, stream>>>(x, w1p, c1b, h1b, gn1a);
    k_x3<<<512, 256, 0, stream>>>(h1b, gn1a, g1w, g1b, k1e, tb);
    k_xsa<<<4096, 256, 0, stream>>>(h1b, gn1a, g1w, g1b, w2e, tb, gnsa);
    k_conv2<<<4096, 256, 0, stream>>>(tb, gnsa, gsw, gsb, w2p, c2b, rawb, gn2a);
    k_final<<<4096, 256, 0, stream>>>(x, rawb, gn2a, g2w, g2b, out);
}

// Round 12
// 342.220 us; speedup vs baseline: 1.4045x; 1.0071x over previous
//
#include <hip/hip_runtime.h>
#include <math.h>

// Problem constants
#define HW   16384        // 128*128
#define CC   256
#define cC   64
#define BB   16
#define CHW  (CC*HW)      // 4194304
#define cHW  (cC*HW)      // 1048576

// ws float offsets (ws_size = 1 GiB)
#define WS_TB    0                      // t bf16
#define WS_H1B   8388608                // h1 bf16
#define WS_RAWB  16777216               // conv2 raw bf16
#define WS_W2E   50331648
#define WS_K1E   (WS_W2E + 5184)
#define WS_GN1A  (WS_K1E + 16)
#define WS_GNSA  (WS_GN1A + 512)
#define WS_GN2A  (WS_GNSA + 512)
#define WS_W1P   (WS_GN2A + 512)
#define WS_W2P   (WS_W1P + 8192)

typedef __attribute__((ext_vector_type(8))) short bf16x8;
typedef __attribute__((ext_vector_type(4))) float f32x4;

__device__ inline unsigned short f2bf(float f) {
    union { float f; unsigned u; } c; c.f = f;
    unsigned r = c.u + 0x7FFFu + ((c.u >> 16) & 1u);
    return (unsigned short)(r >> 16);
}
__device__ inline float bf2f(unsigned short h) {
    union { unsigned u; float f; } c; c.u = ((unsigned)h) << 16; return c.f;
}

// ---------------------------------------------------------------------------
// K0: effective kernels; zero GN accum; pack conv weights into MFMA frag order
// ---------------------------------------------------------------------------
__global__ void k_setup(const float* __restrict__ W1, const float* __restrict__ W2,
                        const float* __restrict__ c1w, const float* __restrict__ c2w,
                        float* __restrict__ k1e, float* __restrict__ w2e,
                        float* __restrict__ accz, unsigned short* __restrict__ w1p,
                        unsigned short* __restrict__ w2p) {
    __shared__ float tapsum[81];
    __shared__ float a2s[4];
    int tdx = threadIdx.x;
    for (int i = tdx; i < 1536; i += 128) accz[i] = 0.f;
    for (int e = tdx; e < 16384; e += 128) {
        int fi = e >> 9, rem = e & 511;
        int l = rem >> 3, j = rem & 7;
        int ks = fi >> 2, nf = fi & 3;
        int c = ks * 32 + (l >> 4) * 8 + j;
        int oc = nf * 16 + (l & 15);
        w1p[e] = f2bf(c1w[oc * 256 + c]);
    }
    for (int e = tdx; e < 16384; e += 128) {
        int fi = e >> 9, rem = e & 511;
        int l = rem >> 3, j = rem & 7;
        int ks = fi >> 4, nfg = fi & 15;
        int c = ks * 32 + (l >> 4) * 8 + j;
        int oc = nfg * 16 + (l & 15);
        w2p[e] = f2bf(c2w[oc * 64 + c]);
    }
    if (tdx < 81) {
        float s = 0.f;
        for (int ch = 0; ch < 64; ++ch) s += W2[ch * 81 + tdx];
        tapsum[tdx] = s;
    }
    __syncthreads();
    if (tdx == 0) {
        float ring[4] = {0.f, 0.f, 0.f, 0.f};
        for (int i = 0; i < 9; ++i)
            for (int j = 0; j < 9; ++j) {
                int d = max(abs(i - 4), abs(j - 4));
                int r = (d <= 1) ? 0 : (d - 1);
                ring[r] += tapsum[i * 9 + j];
            }
        float den2[4] = {576.f, 1024.f, 1536.f, 2048.f};
        float v[4], mx = -1e30f;
        for (int p = 0; p < 4; ++p) { v[p] = ring[p] / den2[p]; mx = fmaxf(mx, v[p]); }
        float se = 0.f;
        for (int p = 0; p < 4; ++p) { v[p] = expf(v[p] - mx); se += v[p]; }
        for (int p = 0; p < 4; ++p) a2s[p] = v[p] / se;
        float k1[9];
        for (int k = 0; k < 9; ++k) k1[k] = W1[k];
        float num[4];
        num[0] = k1[3] + k1[4] + k1[5];
        num[1] = k1[2] + k1[6];
        num[2] = k1[1] + k1[7];
        num[3] = k1[0] + k1[8];
        float den1[4] = {3.f, 2.f, 2.f, 2.f};
        mx = -1e30f;
        for (int p = 0; p < 4; ++p) { v[p] = num[p] / den1[p]; mx = fmaxf(mx, v[p]); }
        se = 0.f;
        for (int p = 0; p < 4; ++p) { v[p] = expf(v[p] - mx); se += v[p]; }
        float a1[4];
        for (int p = 0; p < 4; ++p) a1[p] = v[p] / se;
        float s1arr[5];
        s1arr[0] = 1.f; s1arr[1] = 1.f;
        s1arr[4] = a1[3]; s1arr[3] = a1[2] + a1[3]; s1arr[2] = a1[1] + s1arr[3];
        for (int k = 0; k < 9; ++k) { int d = abs(k - 4); k1e[k] = k1[k] * s1arr[d]; }
    }
    __syncthreads();
    float s2arr[5];
    s2arr[0] = 1.f; s2arr[1] = 1.f;
    s2arr[4] = a2s[3]; s2arr[3] = a2s[2] + a2s[3]; s2arr[2] = a2s[1] + s2arr[3];
    for (int idx = tdx; idx < 64 * 81; idx += 128) {
        int tap = idx % 81;
        int i = tap / 9, j = tap - i * 9;
        int d = max(abs(i - 4), abs(j - 4));
        w2e[idx] = W2[idx] * s2arr[d];
    }
}

// ---------------------------------------------------------------------------
// GN affine helper: from accum pair -> scale/shift for channel ch
// ---------------------------------------------------------------------------
__device__ inline void gn_affine(const float* __restrict__ acc, int b, int g,
                                 float inv_n, const float* __restrict__ gw,
                                 const float* __restrict__ gb, int ch,
                                 float& sc, float& sh) {
    float s = acc[(b * 16 + g) * 2], ss = acc[(b * 16 + g) * 2 + 1];
    float mu = s * inv_n;
    float var = ss * inv_n - mu * mu;
    float rstd = rsqrtf(var + 1e-5f);
    sc = gw[ch] * rstd;
    sh = gb[ch] - mu * sc;
}

// ---------------------------------------------------------------------------
// K1: conv1 (1x1, 256->64) via bf16 MFMA -> h1 bf16 [ch][p] ; GN1 sums
// ---------------------------------------------------------------------------
__global__ __launch_bounds__(256) void k_conv1(const float* __restrict__ x,
        const unsigned short* __restrict__ w1p, const float* __restrict__ b1,
        unsigned short* __restrict__ h1, float* __restrict__ gn1a) {
    int bid = blockIdx.x;
    int b = bid >> 6, pt = bid & 63;
    int tid = threadIdx.x;
    int w = tid >> 6, lane = tid & 63;
    int l15 = lane & 15, lg = lane >> 4;
    int p_wave = pt * 256 + w * 64;
    const bf16x8* w1v = (const bf16x8*)w1p;
    f32x4 acc[4][4];
#pragma unroll
    for (int mf = 0; mf < 4; ++mf)
#pragma unroll
        for (int nf = 0; nf < 4; ++nf) acc[mf][nf] = (f32x4){0.f, 0.f, 0.f, 0.f};
    const float* xb = x + b * CHW;
#pragma unroll 1
    for (int ks = 0; ks < 8; ++ks) {
        int c0 = ks * 32 + lg * 8;
        bf16x8 afr[4];
#pragma unroll
        for (int mf = 0; mf < 4; ++mf) {
            const float* xp = xb + c0 * HW + p_wave + mf * 16 + l15;
            bf16x8 a;
#pragma unroll
            for (int j = 0; j < 8; ++j) a[j] = (short)f2bf(__builtin_nontemporal_load(xp + j * HW));
            afr[mf] = a;
        }
#pragma unroll
        for (int nf = 0; nf < 4; ++nf) {
            bf16x8 bfr = w1v[(ks * 4 + nf) * 64 + lane];
#pragma unroll
            for (int mf = 0; mf < 4; ++mf)
                acc[mf][nf] = __builtin_amdgcn_mfma_f32_16x16x32_bf16(afr[mf], bfr, acc[mf][nf], 0, 0, 0);
        }
    }
    __shared__ float red[4][16][2];
    unsigned short* hb = h1 + b * cHW;
#pragma unroll
    for (int nf = 0; nf < 4; ++nf) {
        int oc = nf * 16 + l15;
        float bias = b1[oc];
        float s = 0.f, ss = 0.f;
#pragma unroll
        for (int mf = 0; mf < 4; ++mf) {
            f32x4 v = acc[mf][nf];
            v[0] += bias; v[1] += bias; v[2] += bias; v[3] += bias;
            ushort4 hv = make_ushort4(f2bf(v[0]), f2bf(v[1]), f2bf(v[2]), f2bf(v[3]));
            *(ushort4*)(hb + oc * HW + p_wave + mf * 16 + lg * 4) = hv;
            s += v[0] + v[1] + v[2] + v[3];
            ss += v[0] * v[0] + v[1] * v[1] + v[2] * v[2] + v[3] * v[3];
        }
        s += __shfl_xor(s, 16, 64); ss += __shfl_xor(ss, 16, 64);
        s += __shfl_xor(s, 32, 64); ss += __shfl_xor(ss, 32, 64);
        s += __shfl_xor(s, 1, 64);  ss += __shfl_xor(ss, 1, 64);
        s += __shfl_xor(s, 2, 64);  ss += __shfl_xor(ss, 2, 64);
        if (lg == 0 && (l15 & 3) == 0) {
            int g = nf * 4 + (l15 >> 2);
            red[w][g][0] = s; red[w][g][1] = ss;
        }
    }
    __syncthreads();
    if (tid < 32) {
        int g = tid >> 1, c = tid & 1;
        float v = red[0][g][c] + red[1][g][c] + red[2][g][c] + red[3][g][c];
        atomicAdd(&gn1a[(b * 16 + g) * 2 + c], v);
    }
}

// ---------------------------------------------------------------------------
// K3: channel-dim 9-tap conv (pad 4) -> t (bf16) ; 2 positions/thread ;
//     GN1 affine computed inline from gn1a
// ---------------------------------------------------------------------------
__global__ __launch_bounds__(256) void k_x3(const unsigned short* __restrict__ h1,
        const float* __restrict__ gn1a, const float* __restrict__ g1w,
        const float* __restrict__ g1b, const float* __restrict__ k1e,
        unsigned short* __restrict__ t) {
    int i = blockIdx.x * 256 + threadIdx.x;     // 0..131071
    int b = i >> 13, p = (i & 8191) * 2;
    __shared__ float lsc[64], lsh[64], lke[9];
    if (threadIdx.x < 64) {
        int ch = threadIdx.x;
        float sc, sh;
        gn_affine(gn1a, b, ch >> 2, 1.f / 65536.f, g1w, g1b, ch, sc, sh);
        lsc[ch] = sc; lsh[ch] = sh;
    }
    if (threadIdx.x < 9) lke[threadIdx.x] = k1e[threadIdx.x];
    __syncthreads();
    const unsigned short* hb = h1 + b * cHW + p;
    float2 win[9];
#pragma unroll
    for (int k = 0; k < 9; ++k) {
        int ch = k - 4;
        if (ch >= 0) {
            ushort2 hv = *(const ushort2*)(hb + ch * HW);
            float s = lsc[ch], h = lsh[ch];
            win[k] = make_float2(fmaf(bf2f(hv.x), s, h), fmaf(bf2f(hv.y), s, h));
        } else win[k] = make_float2(0.f, 0.f);
    }
    unsigned short* tb = t + b * cHW + p;
#pragma unroll
    for (int ch = 0; ch < 64; ++ch) {
        float2 s = make_float2(0.f, 0.f);
#pragma unroll
        for (int k = 0; k < 9; ++k) {
            float kv = lke[k];
            s.x = fmaf(win[k].x, kv, s.x);
            s.y = fmaf(win[k].y, kv, s.y);
        }
        *(ushort2*)(tb + ch * HW) = make_ushort2(f2bf(s.x), f2bf(s.y));
#pragma unroll
        for (int k = 0; k < 8; ++k) win[k] = win[k + 1];
        int nc = ch + 5;
        if (nc < 64) {
            ushort2 hv = *(const ushort2*)(hb + nc * HW);
            float sN = lsc[nc], hN = lsh[nc];
            win[8] = make_float2(fmaf(bf2f(hv.x), sN, hN), fmaf(bf2f(hv.y), sN, hN));
        } else win[8] = make_float2(0.f, 0.f);
    }
}

// ---------------------------------------------------------------------------
// K4: depthwise 9x9 spatial conv ; t += x_sa (bf16 RMW) ; GN_s sums ;
//     GN1 affine (single channel) computed inline
// ---------------------------------------------------------------------------
__global__ __launch_bounds__(256) void k_xsa(const unsigned short* __restrict__ h1,
        const float* __restrict__ gn1a, const float* __restrict__ g1w,
        const float* __restrict__ g1b, const float* __restrict__ w2e,
        unsigned short* __restrict__ t, float* __restrict__ gnsa) {
    int bid = blockIdx.x;
    int b = bid >> 8, ch = (bid >> 2) & 63, rt = bid & 3;
    int r0 = rt * 32;
    int tid = threadIdx.x;
    float sc, sh;
    gn_affine(gn1a, b, ch >> 2, 1.f / 65536.f, g1w, g1b, ch, sc, sh);
    const unsigned short* hp = h1 + b * cHW + ch * HW;
    __shared__ float tile[40 * 136];            // 21.25 KB
    for (int li = tid; li < 40 * 34; li += 256) {
        int row = li / 34, c4 = li - row * 34;
        int col = c4 * 4;
        int gr = r0 - 4 + row;
        float4 z = make_float4(0.f, 0.f, 0.f, 0.f);
        if (gr >= 0 && gr < 128 && c4 >= 1 && c4 <= 32) {
            int gc = col - 4;
            ushort4 hv = *(const ushort4*)(hp + gr * 128 + gc);
            z = make_float4(fmaf(bf2f(hv.x), sc, sh), fmaf(bf2f(hv.y), sc, sh),
                            fmaf(bf2f(hv.z), sc, sh), fmaf(bf2f(hv.w), sc, sh));
        }
        *(float4*)&tile[row * 136 + col] = z;
    }
    __syncthreads();
    int r4g = tid >> 5, c4g = tid & 31;
    int orow0 = r4g * 4, oc0 = c4g * 4;
    const float* wch = w2e + ch * 81;
    float acc[4][4];
#pragma unroll
    for (int r = 0; r < 4; ++r)
#pragma unroll
        for (int k = 0; k < 4; ++k) acc[r][k] = 0.f;
#pragma unroll
    for (int d = 0; d < 12; ++d) {
        const float* lr = &tile[(orow0 + d) * 136 + oc0];
        float v[12];
        *(float4*)&v[0] = *(const float4*)lr;
        *(float4*)&v[4] = *(const float4*)(lr + 4);
        *(float4*)&v[8] = *(const float4*)(lr + 8);
#pragma unroll
        for (int r = 0; r < 4; ++r) {
            if (r <= d && d - r <= 8) {
                const int i = d - r;
#pragma unroll
                for (int j = 0; j < 9; ++j) {
                    float wv = wch[i * 9 + j];
                    acc[r][0] = fmaf(v[j + 0], wv, acc[r][0]);
                    acc[r][1] = fmaf(v[j + 1], wv, acc[r][1]);
                    acc[r][2] = fmaf(v[j + 2], wv, acc[r][2]);
                    acc[r][3] = fmaf(v[j + 3], wv, acc[r][3]);
                }
            }
        }
    }
    float s = 0.f, ss = 0.f;
    unsigned short* tpb = t + b * cHW + ch * HW + (r0 + orow0) * 128 + oc0;
#pragma unroll
    for (int r = 0; r < 4; ++r) {
        unsigned short* tp = tpb + r * 128;
        ushort4 tv = *(const ushort4*)tp;
        float r0v = bf2f(tv.x) + acc[r][0];
        float r1v = bf2f(tv.y) + acc[r][1];
        float r2v = bf2f(tv.z) + acc[r][2];
        float r3v = bf2f(tv.w) + acc[r][3];
        *(ushort4*)tp = make_ushort4(f2bf(r0v), f2bf(r1v), f2bf(r2v), f2bf(r3v));
        s += r0v + r1v + r2v + r3v;
        ss += r0v * r0v + r1v * r1v + r2v * r2v + r3v * r3v;
    }
#pragma unroll
    for (int off = 32; off; off >>= 1) { s += __shfl_xor(s, off, 64); ss += __shfl_xor(ss, off, 64); }
    __shared__ float rs[4], rss[4];
    int lane = tid & 63, wv2 = tid >> 6;
    if (lane == 0) { rs[wv2] = s; rss[wv2] = ss; }
    __syncthreads();
    if (tid == 0) {
        int gi = (b * 16 + (ch >> 2)) * 2;
        atomicAdd(&gnsa[gi], rs[0] + rs[1] + rs[2] + rs[3]);
        atomicAdd(&gnsa[gi + 1], rss[0] + rss[1] + rss[2] + rss[3]);
    }
}

// ---------------------------------------------------------------------------
// K6: conv2 (1x1, 64->256) via bf16 MFMA.
// NEW: block = 64 pos x 256 oc (4 waves, one oc-quadrant each). The
// normalized+relu'd t panel (64ch x 64pos bf16) is staged ONCE in LDS and
// shared by all 4 waves -> t global reads halved, A-frag gathers from LDS.
// ---------------------------------------------------------------------------
#define ROWU 68   // padded u16 row stride for the 64-pos LDS panel

__global__ __launch_bounds__(256) void k_conv2(const unsigned short* __restrict__ t,
        const float* __restrict__ gnsa, const float* __restrict__ gsw,
        const float* __restrict__ gsb, const unsigned short* __restrict__ w2p,
        const float* __restrict__ b2, unsigned short* __restrict__ raw,
        float* __restrict__ gn2a) {
    int bid = blockIdx.x;
    int b = bid >> 8, pt = bid & 255;
    int p0 = pt * 64;
    int tid = threadIdx.x;
    int w = tid >> 6, lane = tid & 63;
    int l15 = lane & 15, lg = lane >> 4;
    __shared__ float lsc[64], lsh[64];
    __shared__ unsigned short tps[64 * ROWU];   // 8.5 KB
    __shared__ float red[4][4][2];
    if (tid < 64) {
        float sc, sh;
        gn_affine(gnsa, b, tid >> 2, 1.f / 65536.f, gsw, gsb, tid, sc, sh);
        lsc[tid] = sc; lsh[tid] = sh;
    }
    __syncthreads();
    // stage normalized panel: thread -> ch = tid>>2, chunks (tid&3), (tid&3)+4
    {
        int ch = tid >> 2, c8 = tid & 3;
        float sc = lsc[ch], sh = lsh[ch];
        const unsigned short* tg = t + b * cHW + ch * HW + p0;
#pragma unroll
        for (int half = 0; half < 2; ++half) {
            int off = (c8 + half * 4) * 8;
            ushort4 a0 = *(const ushort4*)(tg + off);
            ushort4 a1 = *(const ushort4*)(tg + off + 4);
            ushort4 o0, o1;
            o0.x = f2bf(fmaxf(fmaf(bf2f(a0.x), sc, sh), 0.f));
            o0.y = f2bf(fmaxf(fmaf(bf2f(a0.y), sc, sh), 0.f));
            o0.z = f2bf(fmaxf(fmaf(bf2f(a0.z), sc, sh), 0.f));
            o0.w = f2bf(fmaxf(fmaf(bf2f(a0.w), sc, sh), 0.f));
            o1.x = f2bf(fmaxf(fmaf(bf2f(a1.x), sc, sh), 0.f));
            o1.y = f2bf(fmaxf(fmaf(bf2f(a1.y), sc, sh), 0.f));
            o1.z = f2bf(fmaxf(fmaf(bf2f(a1.z), sc, sh), 0.f));
            o1.w = f2bf(fmaxf(fmaf(bf2f(a1.w), sc, sh), 0.f));
            *(ushort4*)(&tps[ch * ROWU + off]) = o0;
            *(ushort4*)(&tps[ch * ROWU + off + 4]) = o1;
        }
    }
    __syncthreads();
    const bf16x8* w2v = (const bf16x8*)w2p;
    f32x4 acc[4][4];
#pragma unroll
    for (int mf = 0; mf < 4; ++mf)
#pragma unroll
        for (int nf = 0; nf < 4; ++nf) acc[mf][nf] = (f32x4){0.f, 0.f, 0.f, 0.f};
#pragma unroll
    for (int ks = 0; ks < 2; ++ks) {
        int kb = ks * 32 + lg * 8;
        bf16x8 afr[4];
#pragma unroll
        for (int mf = 0; mf < 4; ++mf) {
            int pos = mf * 16 + l15;
            bf16x8 a;
#pragma unroll
            for (int j = 0; j < 8; ++j) a[j] = (short)tps[(kb + j) * ROWU + pos];
            afr[mf] = a;
        }
#pragma unroll
        for (int nf = 0; nf < 4; ++nf) {
            int fi = ks * 16 + (w * 4 + nf);
            bf16x8 bfr = w2v[fi * 64 + lane];
#pragma unroll
            for (int mf = 0; mf < 4; ++mf)
                acc[mf][nf] = __builtin_amdgcn_mfma_f32_16x16x32_bf16(afr[mf], bfr, acc[mf][nf], 0, 0, 0);
        }
    }
    // epilogue: wave w owns oc [w*64, w*64+64)
    int oc0 = w * 64;
    unsigned short* ob = raw + b * CHW;
    float sred[4], ssred[4];
#pragma unroll
    for (int nf = 0; nf < 4; ++nf) {
        int oc = oc0 + nf * 16 + l15;
        float bias = b2[oc];
        float s = 0.f, ss = 0.f;
#pragma unroll
        for (int mf = 0; mf < 4; ++mf) {
            f32x4 v = acc[mf][nf];
            v[0] += bias; v[1] += bias; v[2] += bias; v[3] += bias;
            ushort4 hv = make_ushort4(f2bf(v[0]), f2bf(v[1]), f2bf(v[2]), f2bf(v[3]));
            *(ushort4*)(ob + oc * HW + p0 + mf * 16 + lg * 4) = hv;
            s += v[0] + v[1] + v[2] + v[3];
            ss += v[0] * v[0] + v[1] * v[1] + v[2] * v[2] + v[3] * v[3];
        }
#pragma unroll
        for (int off = 32; off; off >>= 1) { s += __shfl_xor(s, off, 64); ss += __shfl_xor(ss, off, 64); }
        sred[nf] = s; ssred[nf] = ss;
    }
    if (lane == 0) {
#pragma unroll
        for (int nf = 0; nf < 4; ++nf) { red[w][nf][0] = sred[nf]; red[w][nf][1] = ssred[nf]; }
    }
    __syncthreads();
    if (tid < 32) {
        int w_ = tid >> 3, nf = (tid >> 1) & 3, c = tid & 1;
        int g = w_ * 4 + nf;
        atomicAdd(&gn2a[(b * 16 + g) * 2 + c], red[w_][nf][c]);
    }
}

// ---------------------------------------------------------------------------
// K8: out = relu(GN2(raw)) + x ; inline GN2 affine from gn2a ; coalesced 4/thread
// ---------------------------------------------------------------------------
__global__ __launch_bounds__(256) void k_final(const float* __restrict__ x,
        const unsigned short* __restrict__ raw, const float* __restrict__ gn2a,
        const float* __restrict__ g2w, const float* __restrict__ g2b,
        float* __restrict__ out) {
    int tid = blockIdx.x * blockDim.x + threadIdx.x;
    const int total4 = (BB * CHW) / 4;
    int stride = gridDim.x * blockDim.x;
    for (int i = tid; i < total4; i += stride) {
        int e = i * 4;
        int b = e >> 22;
        int o = (e >> 14) & 255;
        float s, h;
        gn_affine(gn2a, b, o >> 4, 1.f / 262144.f, g2w, g2b, o, s, h);
        ushort4 rv = ((const ushort4*)raw)[i];
        f32x4 xv = __builtin_nontemporal_load((const f32x4*)x + i);
        f32x4 r;
        r[0] = fmaxf(fmaf(bf2f(rv.x), s, h), 0.f) + xv[0];
        r[1] = fmaxf(fmaf(bf2f(rv.y), s, h), 0.f) + xv[1];
        r[2] = fmaxf(fmaf(bf2f(rv.z), s, h), 0.f) + xv[2];
        r[3] = fmaxf(fmaf(bf2f(rv.w), s, h), 0.f) + xv[3];
        __builtin_nontemporal_store(r, (f32x4*)out + i);
    }
}

// ---------------------------------------------------------------------------
extern "C" void kernel_launch(void* const* d_in, const int* in_sizes, int n_in,
                              void* d_out, int out_size, void* d_ws, size_t ws_size,
                              hipStream_t stream) {
    (void)in_sizes; (void)n_in; (void)out_size; (void)ws_size;
    const float* x   = (const float*)d_in[0];
    const float* W1  = (const float*)d_in[1];
    const float* W2  = (const float*)d_in[2];
    const float* c1w = (const float*)d_in[3];
    const float* c1b = (const float*)d_in[4];
    const float* c2w = (const float*)d_in[5];
    const float* c2b = (const float*)d_in[6];
    const float* g1w = (const float*)d_in[7];
    const float* g1b = (const float*)d_in[8];
    const float* gsw = (const float*)d_in[9];
    const float* gsb = (const float*)d_in[10];
    const float* g2w = (const float*)d_in[11];
    const float* g2b = (const float*)d_in[12];
    float* out = (float*)d_out;
    float* ws  = (float*)d_ws;

    unsigned short* tb   = (unsigned short*)(ws + WS_TB);
    unsigned short* h1b  = (unsigned short*)(ws + WS_H1B);
    unsigned short* rawb = (unsigned short*)(ws + WS_RAWB);
    float* w2e  = ws + WS_W2E;
    float* k1e  = ws + WS_K1E;
    float* gn1a = ws + WS_GN1A;
    float* gnsa = ws + WS_GNSA;
    float* gn2a = ws + WS_GN2A;
    unsigned short* w1p = (unsigned short*)(ws + WS_W1P);
    unsigned short* w2p = (unsigned short*)(ws + WS_W2P);

    k_setup<<<1, 128, 0, stream>>>(W1, W2, c1w, c2w, k1e, w2e, gn1a, w1p, w2p);
    k_conv1<<<1024, 256, 0, stream>>>(x, w1p, c1b, h1b, gn1a);
    k_x3<<<512, 256, 0, stream>>>(h1b, gn1a, g1w, g1b, k1e, tb);
    k_xsa<<<4096, 256, 0, stream>>>(h1b, gn1a, g1w, g1b, w2e, tb, gnsa);
    k_conv2<<<4096, 256, 0, stream>>>(tb, gnsa, gsw, gsb, w2p, c2b, rawb, gn2a);
    k_final<<<4096, 256, 0, stream>>>(x, rawb, gn2a, g2w, g2b, out);
}